// Round 5
// baseline (214.683 us; speedup 1.0000x reference)
//
#include <hip/hip_runtime.h>
#include <math.h>

#define NTH 256          // 4 waves per block
#define SPB 8            // samples per block
#define WS_FLOATS_PER_BLOCK 6144
typedef float float8 __attribute__((ext_vector_type(8)));

__device__ __forceinline__ float waveSum(float v) {
#pragma unroll
  for (int off = 32; off; off >>= 1) v += __shfl_xor(v, off, 64);
  return v;
}

__device__ __forceinline__ float siluf(float x) { return x / (1.0f + expf(-x)); }

__device__ __forceinline__ float permSum(const float se0, const float se1,
                                         const float se2, const float se3,
                                         const float se4, float Z, int lane) {
  float psum = 0.0f;
#pragma unroll
  for (int pp = 0; pp < 2; ++pp) {
    int p = lane + pp * 64;
    if (p < 120) {
      int rem = p;
      unsigned avail = 0x43210u;
      float c = 0.0f;
      float prod = Z;
#pragma unroll
      for (int j = 0; j < 4; ++j) {
        const int fct = (j == 0) ? 24 : (j == 1) ? 6 : (j == 2) ? 2 : 1;
        int q = rem / fct; rem -= q * fct;
        int sh = q * 4;
        int dg = (avail >> sh) & 0xF;
        avail = (avail & ((1u << sh) - 1u)) | ((avail >> (sh + 4)) << sh);
        float ev = (dg == 0) ? se0 : (dg == 1) ? se1 : (dg == 2) ? se2
                 : (dg == 3) ? se3 : se4;
        c += ev;
        prod *= (Z - c);
      }
      psum += 1.0f / prod;
    }
  }
  return psum;
}

// Selection + PL for one sample given logits in `lv` (per-lane), exp in `ev`,
// partition Z. Writes config to gout, returns lp (lane 0 valid-ish: wave-uniform).
__device__ __forceinline__ float selectAndPL(float lv, float ev, float Z,
                                             const float* __restrict__ u64,
                                             float* __restrict__ gout,
                                             int lane, int* sel_i_out) {
  float u = u64[lane];
  float g = -logf(-logf(fmaxf(u, 1e-10f)));
  float vcur = lv + g;
  float sel_e[5];
#pragma unroll
  for (int r = 0; r < 5; ++r) {
    float bv = vcur; int bi = lane;
#pragma unroll
    for (int off = 32; off; off >>= 1) {
      float ov = __shfl_xor(bv, off, 64);
      int   oi = __shfl_xor(bi, off, 64);
      if (ov > bv || (ov == bv && oi < bi)) { bv = ov; bi = oi; }
    }
    if (sel_i_out) sel_i_out[r] = bi;
    sel_e[r] = __shfl(ev, bi, 64);
    if (lane == bi) vcur = -INFINITY;
  }
  float isSel = (vcur == -INFINITY) ? 1.0f : 0.0f;
  gout[lane] = isSel;
  float sl = waveSum(isSel != 0.0f ? lv : 0.0f);
  float S  = waveSum(permSum(sel_e[0], sel_e[1], sel_e[2], sel_e[3],
                             sel_e[4], Z, lane));
  return sl + logf(S);
}

__global__ __launch_bounds__(NTH, 4)
void pcf_smem(const float* __restrict__ ua, const float* __restrict__ ub,
              const float* __restrict__ alog, const float* __restrict__ W1,
              const float* __restrict__ b1, const float* __restrict__ W2,
              const float* __restrict__ b2, const float* __restrict__ V1,
              const float* __restrict__ c1, const float* __restrict__ V2,
              const float* __restrict__ c2, const float* __restrict__ V3,
              const float* __restrict__ c3, float* __restrict__ out,
              float* __restrict__ ws)
{
  __shared__ float sP[4 * SPB * 64];   // per-wave partials (8 KB)
  __shared__ float sBL[SPB * 64];      // beta logits (2 KB)
  __shared__ int   sSelA[SPB * 5];
  __shared__ float sLpA[SPB];

  const int t    = threadIdx.x;
  const int lane = t & 63;
  const int wv   = t >> 6;
  const int bbase = blockIdx.x * SPB;

  float* wsb  = ws + (size_t)blockIdx.x * WS_FLOATS_PER_BLOCK;
  float* hT   = wsb;            // [128][SPB]
  float* ctxT = wsb + 1024;     // [64][SPB]
  float* z1T  = wsb + 1536;     // [256][SPB]
  float* z2T  = wsb + 3584;     // [256][SPB]

  //============ Phase A: alpha top-5 + PL (2 samples per wave) ============
  {
    float la = alog[lane];
    float ea = expf(la);
    float Za = waveSum(ea);
#pragma unroll
    for (int s2 = 0; s2 < 2; ++s2) {
      int sBlk = wv * 2 + s2;
      int b = bbase + sBlk;
      int sel_i[5];
      float lp = selectAndPL(la, ea, Za, ua + (size_t)b * 64,
                             out + (size_t)b * 128, lane, sel_i);
      if (lane == 0) {
        sLpA[sBlk] = lp;
#pragma unroll
        for (int r = 0; r < 5; ++r) sSelA[sBlk * 5 + r] = sel_i[r];
      }
    }
  }
  __syncthreads();

  //============ Phase H: hT[j][s] = silu(b1 + sum 5 W1 rows) ============
  {
    int s = t >> 5;            // 0..7
    int j = (t & 31) * 4;      // 0..124
    int i0 = sSelA[s * 5 + 0], i1 = sSelA[s * 5 + 1], i2 = sSelA[s * 5 + 2];
    int i3 = sSelA[s * 5 + 3], i4 = sSelA[s * 5 + 4];
    float4 a = *(const float4*)(b1 + j);
    float4 w;
    w = *(const float4*)(W1 + i0 * 128 + j); a.x += w.x; a.y += w.y; a.z += w.z; a.w += w.w;
    w = *(const float4*)(W1 + i1 * 128 + j); a.x += w.x; a.y += w.y; a.z += w.z; a.w += w.w;
    w = *(const float4*)(W1 + i2 * 128 + j); a.x += w.x; a.y += w.y; a.z += w.z; a.w += w.w;
    w = *(const float4*)(W1 + i3 * 128 + j); a.x += w.x; a.y += w.y; a.z += w.z; a.w += w.w;
    w = *(const float4*)(W1 + i4 * 128 + j); a.x += w.x; a.y += w.y; a.z += w.z; a.w += w.w;
    hT[(j + 0) * SPB + s] = siluf(a.x);
    hT[(j + 1) * SPB + s] = siluf(a.y);
    hT[(j + 2) * SPB + s] = siluf(a.z);
    hT[(j + 3) * SPB + s] = siluf(a.w);
  }
  __syncthreads();

  //============ GEMM1 partial: ctx = h @ W2 (K=128, k-split 4) ============
  {
    float acc[SPB] = {};
    const int kb = 32 * wv;
#pragma unroll 4
    for (int k = kb; k < kb + 32; ++k) {
      float8 x = *(const float8*)(hT + k * SPB);
      float wgt = W2[k * 64 + lane];
#pragma unroll
      for (int s = 0; s < SPB; ++s) acc[s] += x[s] * wgt;
    }
#pragma unroll
    for (int s = 0; s < SPB; ++s) sP[wv * 512 + s * 64 + lane] = acc[s];
  }
  __syncthreads();
  // reduce -> ctxT[c][s]
  {
#pragma unroll
    for (int o = t; o < 512; o += NTH) {
      int s = o >> 6, c = o & 63;
      float v = b2[c] + sP[o] + sP[512 + o] + sP[1024 + o] + sP[1536 + o];
      ctxT[c * SPB + s] = v;
    }
  }
  __syncthreads();

  //============ GEMM2: z1 = silu(ctx @ V1[64:,:]) (col-split 4) ============
  {
    const int c = 64 * wv + lane;
    float acc[SPB];
    float cb = c1[c];
#pragma unroll
    for (int s = 0; s < SPB; ++s) acc[s] = cb;
    const float* wp = V1 + (size_t)64 * 256 + c;
#pragma unroll 4
    for (int k = 0; k < 64; ++k) {
      float8 x = *(const float8*)(ctxT + k * SPB);
      float wgt = wp[k * 256];
#pragma unroll
      for (int s = 0; s < SPB; ++s) acc[s] += x[s] * wgt;
    }
    float4 o0, o1;
    o0.x = siluf(acc[0]); o0.y = siluf(acc[1]); o0.z = siluf(acc[2]); o0.w = siluf(acc[3]);
    o1.x = siluf(acc[4]); o1.y = siluf(acc[5]); o1.z = siluf(acc[6]); o1.w = siluf(acc[7]);
    *(float4*)(z1T + c * SPB)     = o0;
    *(float4*)(z1T + c * SPB + 4) = o1;
  }
  __syncthreads();

  //============ GEMM3: z2 = silu(z1 @ V2) (col-split 4) ============
  {
    const int c = 64 * wv + lane;
    float acc[SPB];
    float cb = c2[c];
#pragma unroll
    for (int s = 0; s < SPB; ++s) acc[s] = cb;
    const float* wp = V2 + c;
#pragma unroll 4
    for (int k = 0; k < 256; ++k) {
      float8 x = *(const float8*)(z1T + k * SPB);
      float wgt = wp[(size_t)k * 256];
#pragma unroll
      for (int s = 0; s < SPB; ++s) acc[s] += x[s] * wgt;
    }
    float4 o0, o1;
    o0.x = siluf(acc[0]); o0.y = siluf(acc[1]); o0.z = siluf(acc[2]); o0.w = siluf(acc[3]);
    o1.x = siluf(acc[4]); o1.y = siluf(acc[5]); o1.z = siluf(acc[6]); o1.w = siluf(acc[7]);
    *(float4*)(z2T + c * SPB)     = o0;
    *(float4*)(z2T + c * SPB + 4) = o1;
  }
  __syncthreads();

  //============ GEMM4 partial: bl = z2 @ V3 (K=256, k-split 4) ============
  {
    float acc[SPB] = {};
    const int kb = 64 * wv;
#pragma unroll 4
    for (int k = kb; k < kb + 64; ++k) {
      float8 x = *(const float8*)(z2T + k * SPB);
      float wgt = V3[k * 64 + lane];
#pragma unroll
      for (int s = 0; s < SPB; ++s) acc[s] += x[s] * wgt;
    }
#pragma unroll
    for (int s = 0; s < SPB; ++s) sP[wv * 512 + s * 64 + lane] = acc[s];
  }
  __syncthreads();
  {
#pragma unroll
    for (int o = t; o < 512; o += NTH) {
      int c = o & 63;
      sBL[o] = c3[c] + sP[o] + sP[512 + o] + sP[1024 + o] + sP[1536 + o];
    }
  }
  __syncthreads();

  //============ Phase B: beta top-5 + PL (2 samples per wave) ============
  {
#pragma unroll
    for (int s2 = 0; s2 < 2; ++s2) {
      int sBlk = wv * 2 + s2;
      int b = bbase + sBlk;
      float blv = sBL[sBlk * 64 + lane];
      float eb = expf(blv);
      float Zb = waveSum(eb);
      float lp = selectAndPL(blv, eb, Zb, ub + (size_t)b * 64,
                             out + (size_t)b * 128 + 64, lane, nullptr);
      if (lane == 0)
        out[(size_t)8192 * 128 + b] = sLpA[sBlk] + lp;
    }
  }
}

//================= Fallback (R4 kernel, no ws needed) =================
#define SPB4 4
__global__ __launch_bounds__(NTH, 8)
void pcf_small(const float* __restrict__ ua, const float* __restrict__ ub,
               const float* __restrict__ alog, const float* __restrict__ W1,
               const float* __restrict__ b1, const float* __restrict__ W2,
               const float* __restrict__ b2, const float* __restrict__ V1,
               const float* __restrict__ c1, const float* __restrict__ V2,
               const float* __restrict__ c2, const float* __restrict__ V3,
               const float* __restrict__ c3, float* __restrict__ out)
{
  __shared__ float sA[SPB4 * 256];
  __shared__ float sB[SPB4 * 256];
  __shared__ float sP[4 * 256];
  __shared__ int   sSelA[SPB4 * 5];
  __shared__ float sLpA[SPB4];

  const int t    = threadIdx.x;
  const int lane = t & 63;
  const int wv   = t >> 6;
  const int bbase = blockIdx.x * SPB4;

  {
    float la = alog[lane];
    float ea = expf(la);
    float Za = waveSum(ea);
    int b = bbase + wv;
    int sel_i[5];
    float lp = selectAndPL(la, ea, Za, ua + (size_t)b * 64,
                           out + (size_t)b * 128, lane, sel_i);
    if (lane == 0) {
      sLpA[wv] = lp;
#pragma unroll
      for (int r = 0; r < 5; ++r) sSelA[wv * 5 + r] = sel_i[r];
    }
  }
  __syncthreads();
  {
    int s = wv;
    int i0 = sSelA[s * 5 + 0], i1 = sSelA[s * 5 + 1], i2 = sSelA[s * 5 + 2];
    int i3 = sSelA[s * 5 + 3], i4 = sSelA[s * 5 + 4];
#pragma unroll
    for (int jh = 0; jh < 2; ++jh) {
      int j = lane + jh * 64;
      float acc = b1[j] + W1[i0 * 128 + j] + W1[i1 * 128 + j]
                + W1[i2 * 128 + j] + W1[i3 * 128 + j] + W1[i4 * 128 + j];
      sA[s * 128 + j] = siluf(acc);
    }
  }
  __syncthreads();
  {
    float acc[SPB4] = {};
    const int kb = 32 * wv;
#pragma unroll 2
    for (int m = 0; m < 8; ++m) {
      int k0 = kb + 4 * m;
      float w0 = W2[(k0 + 0) * 64 + lane];
      float w1 = W2[(k0 + 1) * 64 + lane];
      float w2 = W2[(k0 + 2) * 64 + lane];
      float w3 = W2[(k0 + 3) * 64 + lane];
#pragma unroll
      for (int s = 0; s < SPB4; ++s) {
        float4 x = *(float4*)&sA[s * 128 + k0];
        acc[s] += x.x * w0 + x.y * w1 + x.z * w2 + x.w * w3;
      }
    }
#pragma unroll
    for (int s = 0; s < SPB4; ++s) sP[wv * 256 + s * 64 + lane] = acc[s];
  }
  __syncthreads();
  {
    int o = t;
    float v = b2[o & 63] + sP[o] + sP[256 + o] + sP[512 + o] + sP[768 + o];
    sB[o] = v;
  }
  __syncthreads();
  {
    const int c = 64 * wv + lane;
    float acc[SPB4];
    float cb = c1[c];
#pragma unroll
    for (int s = 0; s < SPB4; ++s) acc[s] = cb;
    const float* wp = V1 + (size_t)64 * 256 + c;
#pragma unroll 4
    for (int m = 0; m < 16; ++m) {
      int k0 = 4 * m;
      float w0 = wp[(k0 + 0) * 256];
      float w1 = wp[(k0 + 1) * 256];
      float w2 = wp[(k0 + 2) * 256];
      float w3 = wp[(k0 + 3) * 256];
#pragma unroll
      for (int s = 0; s < SPB4; ++s) {
        float4 x = *(float4*)&sB[s * 64 + k0];
        acc[s] += x.x * w0 + x.y * w1 + x.z * w2 + x.w * w3;
      }
    }
#pragma unroll
    for (int s = 0; s < SPB4; ++s) sA[s * 256 + c] = siluf(acc[s]);
  }
  __syncthreads();
  {
    const int c = 64 * wv + lane;
    float acc[SPB4];
    float cb = c2[c];
#pragma unroll
    for (int s = 0; s < SPB4; ++s) acc[s] = cb;
    const float* wp = V2 + c;
#pragma unroll 4
    for (int m = 0; m < 64; ++m) {
      int k0 = 4 * m;
      float w0 = wp[(size_t)(k0 + 0) * 256];
      float w1 = wp[(size_t)(k0 + 1) * 256];
      float w2 = wp[(size_t)(k0 + 2) * 256];
      float w3 = wp[(size_t)(k0 + 3) * 256];
#pragma unroll
      for (int s = 0; s < SPB4; ++s) {
        float4 x = *(float4*)&sA[s * 256 + k0];
        acc[s] += x.x * w0 + x.y * w1 + x.z * w2 + x.w * w3;
      }
    }
#pragma unroll
    for (int s = 0; s < SPB4; ++s) sB[s * 256 + c] = siluf(acc[s]);
  }
  __syncthreads();
  {
    float acc[SPB4] = {};
    const int kb = 64 * wv;
#pragma unroll 4
    for (int m = 0; m < 16; ++m) {
      int k0 = kb + 4 * m;
      float w0 = V3[(k0 + 0) * 64 + lane];
      float w1 = V3[(k0 + 1) * 64 + lane];
      float w2 = V3[(k0 + 2) * 64 + lane];
      float w3 = V3[(k0 + 3) * 64 + lane];
#pragma unroll
      for (int s = 0; s < SPB4; ++s) {
        float4 x = *(float4*)&sB[s * 256 + k0];
        acc[s] += x.x * w0 + x.y * w1 + x.z * w2 + x.w * w3;
      }
    }
#pragma unroll
    for (int s = 0; s < SPB4; ++s) sP[wv * 256 + s * 64 + lane] = acc[s];
  }
  __syncthreads();
  {
    int b = bbase + wv;
    float blv = c3[lane] + sP[wv * 64 + lane] + sP[256 + wv * 64 + lane]
              + sP[512 + wv * 64 + lane] + sP[768 + wv * 64 + lane];
    float eb = expf(blv);
    float Zb = waveSum(eb);
    float lp = selectAndPL(blv, eb, Zb, ub + (size_t)b * 64,
                           out + (size_t)b * 128 + 64, lane, nullptr);
    if (lane == 0)
      out[(size_t)8192 * 128 + b] = sLpA[wv] + lp;
  }
}

extern "C" void kernel_launch(void* const* d_in, const int* in_sizes, int n_in,
                              void* d_out, int out_size, void* d_ws, size_t ws_size,
                              hipStream_t stream) {
  const float* ua   = (const float*)d_in[0];
  const float* ub   = (const float*)d_in[1];
  const float* alog = (const float*)d_in[2];
  const float* W1   = (const float*)d_in[3];
  const float* b1   = (const float*)d_in[4];
  const float* W2   = (const float*)d_in[5];
  const float* b2   = (const float*)d_in[6];
  const float* V1   = (const float*)d_in[7];
  const float* c1   = (const float*)d_in[8];
  const float* V2   = (const float*)d_in[9];
  const float* c2   = (const float*)d_in[10];
  const float* V3   = (const float*)d_in[11];
  const float* c3   = (const float*)d_in[12];
  float* out = (float*)d_out;

  const size_t ws_needed = (size_t)(8192 / SPB) * WS_FLOATS_PER_BLOCK * 4;
  if (ws_size >= ws_needed) {
    pcf_smem<<<dim3(8192 / SPB), dim3(NTH), 0, stream>>>(
        ua, ub, alog, W1, b1, W2, b2, V1, c1, V2, c2, V3, c3, out,
        (float*)d_ws);
  } else {
    pcf_small<<<dim3(8192 / SPB4), dim3(NTH), 0, stream>>>(
        ua, ub, alog, W1, b1, W2, b2, V1, c1, V2, c2, V3, c3, out);
  }
}

// Round 6
// 128.957 us; speedup vs baseline: 1.6648x; 1.6648x over previous
//
#include <hip/hip_runtime.h>
#include <math.h>

#define NTH 256
#define KP 264                      // LDS row stride (ushorts), padded
#define OFF_W2 0                    // 4 tiles x 4 ksteps
#define OFF_V1 16384                // 16 x 2
#define OFF_V2 49152                // 16 x 8
#define OFF_V3 180224               // 4 x 8
#define WS_USHORTS 212992
#define MFMA16 __builtin_amdgcn_mfma_f32_16x16x32_bf16

typedef __attribute__((ext_vector_type(8))) short s16x8;
typedef __attribute__((ext_vector_type(8))) unsigned short u16x8;
typedef __attribute__((ext_vector_type(4))) float f32x4;

__device__ __forceinline__ float waveSum(float v) {
#pragma unroll
  for (int off = 32; off; off >>= 1) v += __shfl_xor(v, off, 64);
  return v;
}

__device__ __forceinline__ float siluf(float x) { return x / (1.0f + expf(-x)); }

// Split fp32 into bf16 hi + bf16 lo (round-to-nearest-even).
__device__ __forceinline__ void bsplit(float x, unsigned short& h, unsigned short& l) {
  unsigned u = __float_as_uint(x);
  unsigned hb = (u + 0x7FFFu + ((u >> 16) & 1u)) >> 16;
  float hf = __uint_as_float(hb << 16);
  float lf = x - hf;
  unsigned ul = __float_as_uint(lf);
  unsigned lb = (ul + 0x7FFFu + ((ul >> 16) & 1u)) >> 16;
  h = (unsigned short)hb; l = (unsigned short)lb;
}

__device__ __forceinline__ float permSum(const float se0, const float se1,
                                         const float se2, const float se3,
                                         const float se4, float Z, int lane) {
  float psum = 0.0f;
#pragma unroll
  for (int pp = 0; pp < 2; ++pp) {
    int p = lane + pp * 64;
    if (p < 120) {
      int rem = p;
      unsigned avail = 0x43210u;
      float c = 0.0f;
      float prod = Z;
#pragma unroll
      for (int j = 0; j < 4; ++j) {
        const int fct = (j == 0) ? 24 : (j == 1) ? 6 : (j == 2) ? 2 : 1;
        int q = rem / fct; rem -= q * fct;
        int sh = q * 4;
        int dg = (avail >> sh) & 0xF;
        avail = (avail & ((1u << sh) - 1u)) | ((avail >> (sh + 4)) << sh);
        float ev = (dg == 0) ? se0 : (dg == 1) ? se1 : (dg == 2) ? se2
                 : (dg == 3) ? se3 : se4;
        c += ev;
        prod *= (Z - c);
      }
      psum += 1.0f / prod;
    }
  }
  return psum;
}

__device__ __forceinline__ float selectAndPL(float lv, float ev, float Z,
                                             const float* __restrict__ u64,
                                             float* __restrict__ gout,
                                             int lane, int* sel_i_out) {
  float u = u64[lane];
  float g = -logf(-logf(fmaxf(u, 1e-10f)));
  float vcur = lv + g;
  float sel_e[5];
#pragma unroll
  for (int r = 0; r < 5; ++r) {
    float bv = vcur; int bi = lane;
#pragma unroll
    for (int off = 32; off; off >>= 1) {
      float ov = __shfl_xor(bv, off, 64);
      int   oi = __shfl_xor(bi, off, 64);
      if (ov > bv || (ov == bv && oi < bi)) { bv = ov; bi = oi; }
    }
    if (sel_i_out) sel_i_out[r] = bi;
    sel_e[r] = __shfl(ev, bi, 64);
    if (lane == bi) vcur = -INFINITY;
  }
  float isSel = (vcur == -INFINITY) ? 1.0f : 0.0f;
  gout[lane] = isSel;
  float sl = waveSum(isSel != 0.0f ? lv : 0.0f);
  float S  = waveSum(permSum(sel_e[0], sel_e[1], sel_e[2], sel_e[3],
                             sel_e[4], Z, lane));
  return sl + logf(S);
}

//============ Prep: tile + split weights into fragment order ============
// Layout per matrix: for (ct, ks): 1KB hi block [lane][8] then 1KB lo block.
// Fragment element: n = ct*16 + (lane&15), k = ks*32 + (lane>>4)*8 + j.
__global__ __launch_bounds__(NTH)
void pcf_prep(const float* __restrict__ W2, const float* __restrict__ V1,
              const float* __restrict__ V2, const float* __restrict__ V3,
              unsigned short* __restrict__ ws)
{
  int tid = blockIdx.x * NTH + threadIdx.x;
  const float* src; int N, Ks, dstoff, r;
  if (tid < 1024)       { src = W2;            N = 64;  Ks = 4; dstoff = OFF_W2; r = tid; }
  else if (tid < 3072)  { src = V1 + 64 * 256; N = 256; Ks = 2; dstoff = OFF_V1; r = tid - 1024; }
  else if (tid < 11264) { src = V2;            N = 256; Ks = 8; dstoff = OFF_V2; r = tid - 3072; }
  else                  { src = V3;            N = 64;  Ks = 8; dstoff = OFF_V3; r = tid - 11264; }
  int lane = r & 63, ts = r >> 6;
  int ks = ts % Ks, ct = ts / Ks;
  int n = ct * 16 + (lane & 15);
  int k0 = ks * 32 + (lane >> 4) * 8;
  u16x8 hv, lv;
#pragma unroll
  for (int j = 0; j < 8; ++j) {
    float x = src[(size_t)(k0 + j) * N + n];
    unsigned short h, l;
    bsplit(x, h, l);
    hv[j] = h; lv[j] = l;
  }
  unsigned short* dst = ws + dstoff + (size_t)ts * 1024 + lane * 8;
  *(u16x8*)dst = hv;
  *(u16x8*)(dst + 512) = lv;
}

//============ Main: 16 samples/block, 4 waves, MFMA bf16x2 ============
__global__ __launch_bounds__(NTH, 2)
void pcf_mfma(const float* __restrict__ ua, const float* __restrict__ ub,
              const float* __restrict__ alog, const float* __restrict__ W1,
              const float* __restrict__ b1, const float* __restrict__ b2,
              const float* __restrict__ c1, const float* __restrict__ c2,
              const float* __restrict__ c3,
              const unsigned short* __restrict__ wt, float* __restrict__ out)
{
  __shared__ unsigned short sAhi[16 * KP], sAlo[16 * KP];
  __shared__ unsigned short sBhi[16 * KP], sBlo[16 * KP];
  __shared__ float sBL[16 * 64];
  __shared__ int   sSelA[16 * 5];
  __shared__ float sLpA[16];

  const int t    = threadIdx.x;
  const int lane = t & 63;
  const int wv   = t >> 6;
  const int ln15 = lane & 15;
  const int quad = lane >> 4;
  const int bbase = blockIdx.x * 16;

  //===== Phase A: alpha top-5 + PL (4 samples per wave) =====
  {
    float la = alog[lane];
    float ea = expf(la);
    float Za = waveSum(ea);
#pragma unroll 1
    for (int si = 0; si < 4; ++si) {
      int s = wv * 4 + si;
      int b = bbase + s;
      int sel_i[5];
      float lp = selectAndPL(la, ea, Za, ua + (size_t)b * 64,
                             out + (size_t)b * 128, lane, sel_i);
      if (lane == 0) {
        sLpA[s] = lp;
#pragma unroll
        for (int r = 0; r < 5; ++r) sSelA[s * 5 + r] = sel_i[r];
      }
    }
  }
  __syncthreads();

  //===== Phase H: h[s][0..127] = silu(b1 + sum 5 W1 rows) -> sA =====
  {
    int s  = t >> 4;
    int j8 = (t & 15) * 8;
    int i0 = sSelA[s * 5 + 0], i1 = sSelA[s * 5 + 1], i2 = sSelA[s * 5 + 2];
    int i3 = sSelA[s * 5 + 3], i4 = sSelA[s * 5 + 4];
    float v[8];
    {
      const float4* p = (const float4*)(b1 + j8);
      float4 q0 = p[0], q1 = p[1];
      v[0]=q0.x; v[1]=q0.y; v[2]=q0.z; v[3]=q0.w;
      v[4]=q1.x; v[5]=q1.y; v[6]=q1.z; v[7]=q1.w;
    }
    const int rows[5] = { i0, i1, i2, i3, i4 };
#pragma unroll
    for (int r = 0; r < 5; ++r) {
      const float4* p = (const float4*)(W1 + (size_t)rows[r] * 128 + j8);
      float4 q0 = p[0], q1 = p[1];
      v[0]+=q0.x; v[1]+=q0.y; v[2]+=q0.z; v[3]+=q0.w;
      v[4]+=q1.x; v[5]+=q1.y; v[6]+=q1.z; v[7]+=q1.w;
    }
    u16x8 hv, lv;
#pragma unroll
    for (int j = 0; j < 8; ++j) {
      unsigned short h, l;
      bsplit(siluf(v[j]), h, l);
      hv[j] = h; lv[j] = l;
    }
    *(u16x8*)&sAhi[s * KP + j8] = hv;
    *(u16x8*)&sAlo[s * KP + j8] = lv;
  }
  __syncthreads();

  //===== GEMM1: ctx(16x64) = h @ W2 + b2  (K=128, tile ct=wv) =====
  {
    f32x4 acc = {0.f, 0.f, 0.f, 0.f};
#pragma unroll
    for (int ks = 0; ks < 4; ++ks) {
      int ko = ks * 32 + quad * 8;
      s16x8 ah = *(const s16x8*)&sAhi[ln15 * KP + ko];
      s16x8 al = *(const s16x8*)&sAlo[ln15 * KP + ko];
      const unsigned short* tsb = wt + OFF_W2 + (size_t)(wv * 4 + ks) * 1024;
      s16x8 bh = ((const s16x8*)tsb)[lane];
      s16x8 bl = ((const s16x8*)(tsb + 512))[lane];
      acc = MFMA16(ah, bh, acc, 0, 0, 0);
      acc = MFMA16(ah, bl, acc, 0, 0, 0);
      acc = MFMA16(al, bh, acc, 0, 0, 0);
    }
    int col = wv * 16 + ln15;
    float bias = b2[col];
#pragma unroll
    for (int r = 0; r < 4; ++r) {
      unsigned short h, l;
      bsplit(acc[r] + bias, h, l);
      sBhi[(quad * 4 + r) * KP + col] = h;
      sBlo[(quad * 4 + r) * KP + col] = l;
    }
  }
  __syncthreads();

  //===== GEMM2: z1(16x256) = silu(ctx @ V1[64:,:] + c1)  (K=64) =====
  {
    f32x4 acc[4];
#pragma unroll
    for (int i = 0; i < 4; ++i) acc[i] = (f32x4){0.f, 0.f, 0.f, 0.f};
#pragma unroll
    for (int ks = 0; ks < 2; ++ks) {
      int ko = ks * 32 + quad * 8;
      s16x8 ah = *(const s16x8*)&sBhi[ln15 * KP + ko];
      s16x8 al = *(const s16x8*)&sBlo[ln15 * KP + ko];
#pragma unroll
      for (int i = 0; i < 4; ++i) {
        const unsigned short* tsb = wt + OFF_V1 + (size_t)((wv * 4 + i) * 2 + ks) * 1024;
        s16x8 bh = ((const s16x8*)tsb)[lane];
        s16x8 bl = ((const s16x8*)(tsb + 512))[lane];
        acc[i] = MFMA16(ah, bh, acc[i], 0, 0, 0);
        acc[i] = MFMA16(ah, bl, acc[i], 0, 0, 0);
        acc[i] = MFMA16(al, bh, acc[i], 0, 0, 0);
      }
    }
#pragma unroll
    for (int i = 0; i < 4; ++i) {
      int col = (wv * 4 + i) * 16 + ln15;
      float bias = c1[col];
#pragma unroll
      for (int r = 0; r < 4; ++r) {
        unsigned short h, l;
        bsplit(siluf(acc[i][r] + bias), h, l);
        sAhi[(quad * 4 + r) * KP + col] = h;
        sAlo[(quad * 4 + r) * KP + col] = l;
      }
    }
  }
  __syncthreads();

  //===== GEMM3: z2(16x256) = silu(z1 @ V2 + c2)  (K=256) =====
  {
    f32x4 acc[4];
#pragma unroll
    for (int i = 0; i < 4; ++i) acc[i] = (f32x4){0.f, 0.f, 0.f, 0.f};
#pragma unroll 2
    for (int ks = 0; ks < 8; ++ks) {
      int ko = ks * 32 + quad * 8;
      s16x8 ah = *(const s16x8*)&sAhi[ln15 * KP + ko];
      s16x8 al = *(const s16x8*)&sAlo[ln15 * KP + ko];
#pragma unroll
      for (int i = 0; i < 4; ++i) {
        const unsigned short* tsb = wt + OFF_V2 + (size_t)((wv * 4 + i) * 8 + ks) * 1024;
        s16x8 bh = ((const s16x8*)tsb)[lane];
        s16x8 bl = ((const s16x8*)(tsb + 512))[lane];
        acc[i] = MFMA16(ah, bh, acc[i], 0, 0, 0);
        acc[i] = MFMA16(ah, bl, acc[i], 0, 0, 0);
        acc[i] = MFMA16(al, bh, acc[i], 0, 0, 0);
      }
    }
#pragma unroll
    for (int i = 0; i < 4; ++i) {
      int col = (wv * 4 + i) * 16 + ln15;
      float bias = c2[col];
#pragma unroll
      for (int r = 0; r < 4; ++r) {
        unsigned short h, l;
        bsplit(siluf(acc[i][r] + bias), h, l);
        sBhi[(quad * 4 + r) * KP + col] = h;
        sBlo[(quad * 4 + r) * KP + col] = l;
      }
    }
  }
  __syncthreads();

  //===== GEMM4: beta_logits(16x64) = z2 @ V3 + c3  (K=256, tile ct=wv) =====
  {
    f32x4 acc = {0.f, 0.f, 0.f, 0.f};
#pragma unroll
    for (int ks = 0; ks < 8; ++ks) {
      int ko = ks * 32 + quad * 8;
      s16x8 ah = *(const s16x8*)&sBhi[ln15 * KP + ko];
      s16x8 al = *(const s16x8*)&sBlo[ln15 * KP + ko];
      const unsigned short* tsb = wt + OFF_V3 + (size_t)(wv * 8 + ks) * 1024;
      s16x8 bh = ((const s16x8*)tsb)[lane];
      s16x8 bl = ((const s16x8*)(tsb + 512))[lane];
      acc = MFMA16(ah, bh, acc, 0, 0, 0);
      acc = MFMA16(ah, bl, acc, 0, 0, 0);
      acc = MFMA16(al, bh, acc, 0, 0, 0);
    }
    int col = wv * 16 + ln15;
    float bias = c3[col];
#pragma unroll
    for (int r = 0; r < 4; ++r)
      sBL[(quad * 4 + r) * 64 + col] = acc[r] + bias;
  }
  __syncthreads();

  //===== Phase B: beta top-5 + PL (4 samples per wave) =====
  {
#pragma unroll 1
    for (int si = 0; si < 4; ++si) {
      int s = wv * 4 + si;
      int b = bbase + s;
      float blv = sBL[s * 64 + lane];
      float eb = expf(blv);
      float Zb = waveSum(eb);
      float lp = selectAndPL(blv, eb, Zb, ub + (size_t)b * 64,
                             out + (size_t)b * 128 + 64, lane, nullptr);
      if (lane == 0)
        out[(size_t)8192 * 128 + b] = sLpA[s] + lp;
    }
  }
}

//================= Fallback (R4 kernel, no ws needed) =================
#define SPB4 4
__global__ __launch_bounds__(NTH, 8)
void pcf_small(const float* __restrict__ ua, const float* __restrict__ ub,
               const float* __restrict__ alog, const float* __restrict__ W1,
               const float* __restrict__ b1, const float* __restrict__ W2,
               const float* __restrict__ b2, const float* __restrict__ V1,
               const float* __restrict__ c1, const float* __restrict__ V2,
               const float* __restrict__ c2, const float* __restrict__ V3,
               const float* __restrict__ c3, float* __restrict__ out)
{
  __shared__ float sA[SPB4 * 256];
  __shared__ float sB[SPB4 * 256];
  __shared__ float sP[4 * 256];
  __shared__ int   sSelA[SPB4 * 5];
  __shared__ float sLpA[SPB4];

  const int t    = threadIdx.x;
  const int lane = t & 63;
  const int wv   = t >> 6;
  const int bbase = blockIdx.x * SPB4;

  {
    float la = alog[lane];
    float ea = expf(la);
    float Za = waveSum(ea);
    int b = bbase + wv;
    int sel_i[5];
    float lp = selectAndPL(la, ea, Za, ua + (size_t)b * 64,
                           out + (size_t)b * 128, lane, sel_i);
    if (lane == 0) {
      sLpA[wv] = lp;
#pragma unroll
      for (int r = 0; r < 5; ++r) sSelA[wv * 5 + r] = sel_i[r];
    }
  }
  __syncthreads();
  {
    int s = wv;
    int i0 = sSelA[s * 5 + 0], i1 = sSelA[s * 5 + 1], i2 = sSelA[s * 5 + 2];
    int i3 = sSelA[s * 5 + 3], i4 = sSelA[s * 5 + 4];
#pragma unroll
    for (int jh = 0; jh < 2; ++jh) {
      int j = lane + jh * 64;
      float acc = b1[j] + W1[i0 * 128 + j] + W1[i1 * 128 + j]
                + W1[i2 * 128 + j] + W1[i3 * 128 + j] + W1[i4 * 128 + j];
      sA[s * 128 + j] = siluf(acc);
    }
  }
  __syncthreads();
  {
    float acc[SPB4] = {};
    const int kb = 32 * wv;
#pragma unroll 2
    for (int m = 0; m < 8; ++m) {
      int k0 = kb + 4 * m;
      float w0 = W2[(k0 + 0) * 64 + lane];
      float w1 = W2[(k0 + 1) * 64 + lane];
      float w2 = W2[(k0 + 2) * 64 + lane];
      float w3 = W2[(k0 + 3) * 64 + lane];
#pragma unroll
      for (int s = 0; s < SPB4; ++s) {
        float4 x = *(float4*)&sA[s * 128 + k0];
        acc[s] += x.x * w0 + x.y * w1 + x.z * w2 + x.w * w3;
      }
    }
#pragma unroll
    for (int s = 0; s < SPB4; ++s) sP[wv * 256 + s * 64 + lane] = acc[s];
  }
  __syncthreads();
  {
    int o = t;
    float v = b2[o & 63] + sP[o] + sP[256 + o] + sP[512 + o] + sP[768 + o];
    sB[o] = v;
  }
  __syncthreads();
  {
    const int c = 64 * wv + lane;
    float acc[SPB4];
    float cb = c1[c];
#pragma unroll
    for (int s = 0; s < SPB4; ++s) acc[s] = cb;
    const float* wp = V1 + (size_t)64 * 256 + c;
#pragma unroll 4
    for (int m = 0; m < 16; ++m) {
      int k0 = 4 * m;
      float w0 = wp[(k0 + 0) * 256];
      float w1 = wp[(k0 + 1) * 256];
      float w2 = wp[(k0 + 2) * 256];
      float w3 = wp[(k0 + 3) * 256];
#pragma unroll
      for (int s = 0; s < SPB4; ++s) {
        float4 x = *(float4*)&sB[s * 64 + k0];
        acc[s] += x.x * w0 + x.y * w1 + x.z * w2 + x.w * w3;
      }
    }
#pragma unroll
    for (int s = 0; s < SPB4; ++s) sA[s * 256 + c] = siluf(acc[s]);
  }
  __syncthreads();
  {
    const int c = 64 * wv + lane;
    float acc[SPB4];
    float cb = c2[c];
#pragma unroll
    for (int s = 0; s < SPB4; ++s) acc[s] = cb;
    const float* wp = V2 + c;
#pragma unroll 4
    for (int m = 0; m < 64; ++m) {
      int k0 = 4 * m;
      float w0 = wp[(size_t)(k0 + 0) * 256];
      float w1 = wp[(size_t)(k0 + 1) * 256];
      float w2 = wp[(size_t)(k0 + 2) * 256];
      float w3 = wp[(size_t)(k0 + 3) * 256];
#pragma unroll
      for (int s = 0; s < SPB4; ++s) {
        float4 x = *(float4*)&sA[s * 256 + k0];
        acc[s] += x.x * w0 + x.y * w1 + x.z * w2 + x.w * w3;
      }
    }
#pragma unroll
    for (int s = 0; s < SPB4; ++s) sB[s * 256 + c] = siluf(acc[s]);
  }
  __syncthreads();
  {
    float acc[SPB4] = {};
    const int kb = 64 * wv;
#pragma unroll 4
    for (int m = 0; m < 16; ++m) {
      int k0 = kb + 4 * m;
      float w0 = V3[(k0 + 0) * 64 + lane];
      float w1 = V3[(k0 + 1) * 64 + lane];
      float w2 = V3[(k0 + 2) * 64 + lane];
      float w3 = V3[(k0 + 3) * 64 + lane];
#pragma unroll
      for (int s = 0; s < SPB4; ++s) {
        float4 x = *(float4*)&sB[s * 256 + k0];
        acc[s] += x.x * w0 + x.y * w1 + x.z * w2 + x.w * w3;
      }
    }
#pragma unroll
    for (int s = 0; s < SPB4; ++s) sP[wv * 256 + s * 64 + lane] = acc[s];
  }
  __syncthreads();
  {
    int b = bbase + wv;
    float blv = c3[lane] + sP[wv * 64 + lane] + sP[256 + wv * 64 + lane]
              + sP[512 + wv * 64 + lane] + sP[768 + wv * 64 + lane];
    float eb = expf(blv);
    float Zb = waveSum(eb);
    float lp = selectAndPL(blv, eb, Zb, ub + (size_t)b * 64,
                           out + (size_t)b * 128 + 64, lane, nullptr);
    if (lane == 0)
      out[(size_t)8192 * 128 + b] = sLpA[wv] + lp;
  }
}

extern "C" void kernel_launch(void* const* d_in, const int* in_sizes, int n_in,
                              void* d_out, int out_size, void* d_ws, size_t ws_size,
                              hipStream_t stream) {
  const float* ua   = (const float*)d_in[0];
  const float* ub   = (const float*)d_in[1];
  const float* alog = (const float*)d_in[2];
  const float* W1   = (const float*)d_in[3];
  const float* b1   = (const float*)d_in[4];
  const float* W2   = (const float*)d_in[5];
  const float* b2   = (const float*)d_in[6];
  const float* V1   = (const float*)d_in[7];
  const float* c1   = (const float*)d_in[8];
  const float* V2   = (const float*)d_in[9];
  const float* c2   = (const float*)d_in[10];
  const float* V3   = (const float*)d_in[11];
  const float* c3   = (const float*)d_in[12];
  float* out = (float*)d_out;

  if (ws_size >= (size_t)WS_USHORTS * 2) {
    unsigned short* wt = (unsigned short*)d_ws;
    pcf_prep<<<dim3(52), dim3(NTH), 0, stream>>>(W2, V1, V2, V3, wt);
    pcf_mfma<<<dim3(512), dim3(NTH), 0, stream>>>(
        ua, ub, alog, W1, b1, b2, c1, c2, c3, wt, out);
  } else {
    pcf_small<<<dim3(8192 / SPB4), dim3(NTH), 0, stream>>>(
        ua, ub, alog, W1, b1, W2, b2, V1, c1, V2, c2, V3, c3, out);
  }
}

// Round 7
// 117.937 us; speedup vs baseline: 1.8203x; 1.0934x over previous
//
#include <hip/hip_runtime.h>
#include <math.h>

#define NTH 256
#define KP 264                      // LDS row stride (ushorts), padded
#define SPB 8                       // samples per block
#define OFF_W2 0                    // 4 tiles x 4 ksteps
#define OFF_V1 16384                // 16 x 2
#define OFF_V2 49152                // 16 x 8
#define OFF_V3 180224               // 4 x 8
#define WS_USHORTS 212992
#define MFMA16 __builtin_amdgcn_mfma_f32_16x16x32_bf16

typedef __attribute__((ext_vector_type(8))) short s16x8;
typedef __attribute__((ext_vector_type(8))) unsigned short u16x8;
typedef __attribute__((ext_vector_type(4))) unsigned short u16x4;
typedef __attribute__((ext_vector_type(4))) float f32x4;

__device__ __forceinline__ float waveSum(float v) {
#pragma unroll
  for (int off = 32; off; off >>= 1) v += __shfl_xor(v, off, 64);
  return v;
}

__device__ __forceinline__ float siluf(float x) { return x / (1.0f + expf(-x)); }

// Split fp32 into bf16 hi + bf16 lo (round-to-nearest-even).
__device__ __forceinline__ void bsplit(float x, unsigned short& h, unsigned short& l) {
  unsigned u = __float_as_uint(x);
  unsigned hb = (u + 0x7FFFu + ((u >> 16) & 1u)) >> 16;
  float hf = __uint_as_float(hb << 16);
  float lf = x - hf;
  unsigned ul = __float_as_uint(lf);
  unsigned lb = (ul + 0x7FFFu + ((ul >> 16) & 1u)) >> 16;
  h = (unsigned short)hb; l = (unsigned short)lb;
}

__device__ __forceinline__ float permSum(const float se0, const float se1,
                                         const float se2, const float se3,
                                         const float se4, float Z, int lane) {
  float psum = 0.0f;
#pragma unroll
  for (int pp = 0; pp < 2; ++pp) {
    int p = lane + pp * 64;
    if (p < 120) {
      int rem = p;
      unsigned avail = 0x43210u;
      float c = 0.0f;
      float prod = Z;
#pragma unroll
      for (int j = 0; j < 4; ++j) {
        const int fct = (j == 0) ? 24 : (j == 1) ? 6 : (j == 2) ? 2 : 1;
        int q = rem / fct; rem -= q * fct;
        int sh = q * 4;
        int dg = (avail >> sh) & 0xF;
        avail = (avail & ((1u << sh) - 1u)) | ((avail >> (sh + 4)) << sh);
        float ev = (dg == 0) ? se0 : (dg == 1) ? se1 : (dg == 2) ? se2
                 : (dg == 3) ? se3 : se4;
        c += ev;
        prod *= (Z - c);
      }
      psum += 1.0f / prod;
    }
  }
  return psum;
}

__device__ __forceinline__ float selectAndPL(float lv, float ev, float Z,
                                             const float* __restrict__ u64,
                                             float* __restrict__ gout,
                                             int lane, int* sel_i_out) {
  float u = u64[lane];
  float g = -logf(-logf(fmaxf(u, 1e-10f)));
  float vcur = lv + g;
  float sel_e[5];
#pragma unroll
  for (int r = 0; r < 5; ++r) {
    float bv = vcur; int bi = lane;
#pragma unroll
    for (int off = 32; off; off >>= 1) {
      float ov = __shfl_xor(bv, off, 64);
      int   oi = __shfl_xor(bi, off, 64);
      if (ov > bv || (ov == bv && oi < bi)) { bv = ov; bi = oi; }
    }
    if (sel_i_out) sel_i_out[r] = bi;
    sel_e[r] = __shfl(ev, bi, 64);
    if (lane == bi) vcur = -INFINITY;
  }
  float isSel = (vcur == -INFINITY) ? 1.0f : 0.0f;
  gout[lane] = isSel;
  float sl = waveSum(isSel != 0.0f ? lv : 0.0f);
  float S  = waveSum(permSum(sel_e[0], sel_e[1], sel_e[2], sel_e[3],
                             sel_e[4], Z, lane));
  return sl + logf(S);
}

//============ Prep: tile + split weights into fragment order ============
// Layout per matrix: for (ct, ks): 1KB hi block [lane][8] then 1KB lo block.
// Fragment element: n = ct*16 + (lane&15), k = ks*32 + (lane>>4)*8 + j.
__global__ __launch_bounds__(NTH)
void pcf_prep(const float* __restrict__ W2, const float* __restrict__ V1,
              const float* __restrict__ V2, const float* __restrict__ V3,
              unsigned short* __restrict__ ws)
{
  int tid = blockIdx.x * NTH + threadIdx.x;
  const float* src; int N, Ks, dstoff, r;
  if (tid < 1024)       { src = W2;            N = 64;  Ks = 4; dstoff = OFF_W2; r = tid; }
  else if (tid < 3072)  { src = V1 + 64 * 256; N = 256; Ks = 2; dstoff = OFF_V1; r = tid - 1024; }
  else if (tid < 11264) { src = V2;            N = 256; Ks = 8; dstoff = OFF_V2; r = tid - 3072; }
  else                  { src = V3;            N = 64;  Ks = 8; dstoff = OFF_V3; r = tid - 11264; }
  int lane = r & 63, ts = r >> 6;
  int ks = ts % Ks, ct = ts / Ks;
  int n = ct * 16 + (lane & 15);
  int k0 = ks * 32 + (lane >> 4) * 8;
  u16x8 hv, lv;
#pragma unroll
  for (int j = 0; j < 8; ++j) {
    float x = src[(size_t)(k0 + j) * N + n];
    unsigned short h, l;
    bsplit(x, h, l);
    hv[j] = h; lv[j] = l;
  }
  unsigned short* dst = ws + dstoff + (size_t)ts * 1024 + lane * 8;
  *(u16x8*)dst = hv;
  *(u16x8*)(dst + 512) = lv;
}

//============ Main: 8 samples/block, 4 waves, MFMA bf16x2 ============
// M rows 8..15 of the MFMA tiles carry garbage; they only ever feed dead
// C rows and dead LDS rows (all tile arrays are 16 rows tall), never outputs.
__global__ __launch_bounds__(NTH, 4)
void pcf_mfma(const float* __restrict__ ua, const float* __restrict__ ub,
              const float* __restrict__ alog, const float* __restrict__ W1,
              const float* __restrict__ b1, const float* __restrict__ b2,
              const float* __restrict__ c1, const float* __restrict__ c2,
              const float* __restrict__ c3,
              const unsigned short* __restrict__ wt, float* __restrict__ out)
{
  __shared__ unsigned short sAhi[16 * KP], sAlo[16 * KP];
  __shared__ unsigned short sBhi[16 * KP], sBlo[16 * KP];
  __shared__ float sBL[16 * 64];   // 16 rows: GEMM4 epilogue writes dead rows 8..15
  __shared__ int   sSelA[SPB * 5];
  __shared__ float sLpA[SPB];

  const int t    = threadIdx.x;
  const int lane = t & 63;
  const int wv   = t >> 6;
  const int ln15 = lane & 15;
  const int quad = lane >> 4;
  const int bbase = blockIdx.x * SPB;

  //===== Phase A: alpha top-5 + PL (2 samples per wave) =====
  {
    float la = alog[lane];
    float ea = expf(la);
    float Za = waveSum(ea);
#pragma unroll 1
    for (int si = 0; si < 2; ++si) {
      int s = wv * 2 + si;
      int b = bbase + s;
      int sel_i[5];
      float lp = selectAndPL(la, ea, Za, ua + (size_t)b * 64,
                             out + (size_t)b * 128, lane, sel_i);
      if (lane == 0) {
        sLpA[s] = lp;
#pragma unroll
        for (int r = 0; r < 5; ++r) sSelA[s * 5 + r] = sel_i[r];
      }
    }
  }
  __syncthreads();

  //===== Phase H: h[s][0..127] = silu(b1 + sum 5 W1 rows) -> sA =====
  {
    int s  = t >> 5;           // 0..7
    int j4 = (t & 31) * 4;     // 0..124
    const int rows[5] = { sSelA[s * 5 + 0], sSelA[s * 5 + 1], sSelA[s * 5 + 2],
                          sSelA[s * 5 + 3], sSelA[s * 5 + 4] };
    float4 a = *(const float4*)(b1 + j4);
#pragma unroll
    for (int r = 0; r < 5; ++r) {
      float4 w = *(const float4*)(W1 + (size_t)rows[r] * 128 + j4);
      a.x += w.x; a.y += w.y; a.z += w.z; a.w += w.w;
    }
    u16x4 hv, lv;
    unsigned short h, l;
    bsplit(siluf(a.x), h, l); hv[0] = h; lv[0] = l;
    bsplit(siluf(a.y), h, l); hv[1] = h; lv[1] = l;
    bsplit(siluf(a.z), h, l); hv[2] = h; lv[2] = l;
    bsplit(siluf(a.w), h, l); hv[3] = h; lv[3] = l;
    *(u16x4*)&sAhi[s * KP + j4] = hv;
    *(u16x4*)&sAlo[s * KP + j4] = lv;
  }
  __syncthreads();

  //===== GEMM1: ctx(8x64) = h @ W2 + b2  (K=128, tile ct=wv) =====
  {
    f32x4 acc = {0.f, 0.f, 0.f, 0.f};
#pragma unroll
    for (int ks = 0; ks < 4; ++ks) {
      int ko = ks * 32 + quad * 8;
      s16x8 ah = *(const s16x8*)&sAhi[ln15 * KP + ko];
      s16x8 al = *(const s16x8*)&sAlo[ln15 * KP + ko];
      const unsigned short* tsb = wt + OFF_W2 + (size_t)(wv * 4 + ks) * 1024;
      s16x8 bh = ((const s16x8*)tsb)[lane];
      s16x8 bl = ((const s16x8*)(tsb + 512))[lane];
      acc = MFMA16(ah, bh, acc, 0, 0, 0);
      acc = MFMA16(ah, bl, acc, 0, 0, 0);
      acc = MFMA16(al, bh, acc, 0, 0, 0);
    }
    int col = wv * 16 + ln15;
    float bias = b2[col];
#pragma unroll
    for (int r = 0; r < 4; ++r) {
      unsigned short h, l;
      bsplit(acc[r] + bias, h, l);
      sBhi[(quad * 4 + r) * KP + col] = h;
      sBlo[(quad * 4 + r) * KP + col] = l;
    }
  }
  __syncthreads();

  //===== GEMM2: z1(8x256) = silu(ctx @ V1[64:,:] + c1)  (K=64) =====
  {
    f32x4 acc[4];
#pragma unroll
    for (int i = 0; i < 4; ++i) acc[i] = (f32x4){0.f, 0.f, 0.f, 0.f};
#pragma unroll
    for (int ks = 0; ks < 2; ++ks) {
      int ko = ks * 32 + quad * 8;
      s16x8 ah = *(const s16x8*)&sBhi[ln15 * KP + ko];
      s16x8 al = *(const s16x8*)&sBlo[ln15 * KP + ko];
#pragma unroll
      for (int i = 0; i < 4; ++i) {
        const unsigned short* tsb = wt + OFF_V1 + (size_t)((wv * 4 + i) * 2 + ks) * 1024;
        s16x8 bh = ((const s16x8*)tsb)[lane];
        s16x8 bl = ((const s16x8*)(tsb + 512))[lane];
        acc[i] = MFMA16(ah, bh, acc[i], 0, 0, 0);
        acc[i] = MFMA16(ah, bl, acc[i], 0, 0, 0);
        acc[i] = MFMA16(al, bh, acc[i], 0, 0, 0);
      }
    }
#pragma unroll
    for (int i = 0; i < 4; ++i) {
      int col = (wv * 4 + i) * 16 + ln15;
      float bias = c1[col];
#pragma unroll
      for (int r = 0; r < 4; ++r) {
        unsigned short h, l;
        bsplit(siluf(acc[i][r] + bias), h, l);
        sAhi[(quad * 4 + r) * KP + col] = h;
        sAlo[(quad * 4 + r) * KP + col] = l;
      }
    }
  }
  __syncthreads();

  //===== GEMM3: z2(8x256) = silu(z1 @ V2 + c2)  (K=256) =====
  {
    f32x4 acc[4];
#pragma unroll
    for (int i = 0; i < 4; ++i) acc[i] = (f32x4){0.f, 0.f, 0.f, 0.f};
#pragma unroll 2
    for (int ks = 0; ks < 8; ++ks) {
      int ko = ks * 32 + quad * 8;
      s16x8 ah = *(const s16x8*)&sAhi[ln15 * KP + ko];
      s16x8 al = *(const s16x8*)&sAlo[ln15 * KP + ko];
#pragma unroll
      for (int i = 0; i < 4; ++i) {
        const unsigned short* tsb = wt + OFF_V2 + (size_t)((wv * 4 + i) * 8 + ks) * 1024;
        s16x8 bh = ((const s16x8*)tsb)[lane];
        s16x8 bl = ((const s16x8*)(tsb + 512))[lane];
        acc[i] = MFMA16(ah, bh, acc[i], 0, 0, 0);
        acc[i] = MFMA16(ah, bl, acc[i], 0, 0, 0);
        acc[i] = MFMA16(al, bh, acc[i], 0, 0, 0);
      }
    }
#pragma unroll
    for (int i = 0; i < 4; ++i) {
      int col = (wv * 4 + i) * 16 + ln15;
      float bias = c2[col];
#pragma unroll
      for (int r = 0; r < 4; ++r) {
        unsigned short h, l;
        bsplit(siluf(acc[i][r] + bias), h, l);
        sBhi[(quad * 4 + r) * KP + col] = h;
        sBlo[(quad * 4 + r) * KP + col] = l;
      }
    }
  }
  __syncthreads();

  //===== GEMM4: beta_logits(8x64) = z2 @ V3 + c3  (K=256, tile ct=wv) =====
  {
    f32x4 acc = {0.f, 0.f, 0.f, 0.f};
#pragma unroll
    for (int ks = 0; ks < 8; ++ks) {
      int ko = ks * 32 + quad * 8;
      s16x8 ah = *(const s16x8*)&sBhi[ln15 * KP + ko];
      s16x8 al = *(const s16x8*)&sBlo[ln15 * KP + ko];
      const unsigned short* tsb = wt + OFF_V3 + (size_t)(wv * 8 + ks) * 1024;
      s16x8 bh = ((const s16x8*)tsb)[lane];
      s16x8 bl = ((const s16x8*)(tsb + 512))[lane];
      acc = MFMA16(ah, bh, acc, 0, 0, 0);
      acc = MFMA16(ah, bl, acc, 0, 0, 0);
      acc = MFMA16(al, bh, acc, 0, 0, 0);
    }
    int col = wv * 16 + ln15;
    float bias = c3[col];
#pragma unroll
    for (int r = 0; r < 4; ++r)
      sBL[(quad * 4 + r) * 64 + col] = acc[r] + bias;   // rows 8..15 dead
  }
  __syncthreads();

  //===== Phase B: beta top-5 + PL (2 samples per wave) =====
  {
#pragma unroll 1
    for (int si = 0; si < 2; ++si) {
      int s = wv * 2 + si;
      int b = bbase + s;
      float blv = sBL[s * 64 + lane];
      float eb = expf(blv);
      float Zb = waveSum(eb);
      float lp = selectAndPL(blv, eb, Zb, ub + (size_t)b * 64,
                             out + (size_t)b * 128 + 64, lane, nullptr);
      if (lane == 0)
        out[(size_t)8192 * 128 + b] = sLpA[s] + lp;
    }
  }
}

//================= Fallback (R4 kernel, no ws needed) =================
#define SPB4 4
__global__ __launch_bounds__(NTH, 8)
void pcf_small(const float* __restrict__ ua, const float* __restrict__ ub,
               const float* __restrict__ alog, const float* __restrict__ W1,
               const float* __restrict__ b1, const float* __restrict__ W2,
               const float* __restrict__ b2, const float* __restrict__ V1,
               const float* __restrict__ c1, const float* __restrict__ V2,
               const float* __restrict__ c2, const float* __restrict__ V3,
               const float* __restrict__ c3, float* __restrict__ out)
{
  __shared__ float sA[SPB4 * 256];
  __shared__ float sB[SPB4 * 256];
  __shared__ float sP[4 * 256];
  __shared__ int   sSelA[SPB4 * 5];
  __shared__ float sLpA[SPB4];

  const int t    = threadIdx.x;
  const int lane = t & 63;
  const int wv   = t >> 6;
  const int bbase = blockIdx.x * SPB4;

  {
    float la = alog[lane];
    float ea = expf(la);
    float Za = waveSum(ea);
    int b = bbase + wv;
    int sel_i[5];
    float lp = selectAndPL(la, ea, Za, ua + (size_t)b * 64,
                           out + (size_t)b * 128, lane, sel_i);
    if (lane == 0) {
      sLpA[wv] = lp;
#pragma unroll
      for (int r = 0; r < 5; ++r) sSelA[wv * 5 + r] = sel_i[r];
    }
  }
  __syncthreads();
  {
    int s = wv;
    int i0 = sSelA[s * 5 + 0], i1 = sSelA[s * 5 + 1], i2 = sSelA[s * 5 + 2];
    int i3 = sSelA[s * 5 + 3], i4 = sSelA[s * 5 + 4];
#pragma unroll
    for (int jh = 0; jh < 2; ++jh) {
      int j = lane + jh * 64;
      float acc = b1[j] + W1[i0 * 128 + j] + W1[i1 * 128 + j]
                + W1[i2 * 128 + j] + W1[i3 * 128 + j] + W1[i4 * 128 + j];
      sA[s * 128 + j] = siluf(acc);
    }
  }
  __syncthreads();
  {
    float acc[SPB4] = {};
    const int kb = 32 * wv;
#pragma unroll 2
    for (int m = 0; m < 8; ++m) {
      int k0 = kb + 4 * m;
      float w0 = W2[(k0 + 0) * 64 + lane];
      float w1 = W2[(k0 + 1) * 64 + lane];
      float w2 = W2[(k0 + 2) * 64 + lane];
      float w3 = W2[(k0 + 3) * 64 + lane];
#pragma unroll
      for (int s = 0; s < SPB4; ++s) {
        float4 x = *(float4*)&sA[s * 128 + k0];
        acc[s] += x.x * w0 + x.y * w1 + x.z * w2 + x.w * w3;
      }
    }
#pragma unroll
    for (int s = 0; s < SPB4; ++s) sP[wv * 256 + s * 64 + lane] = acc[s];
  }
  __syncthreads();
  {
    int o = t;
    float v = b2[o & 63] + sP[o] + sP[256 + o] + sP[512 + o] + sP[768 + o];
    sB[o] = v;
  }
  __syncthreads();
  {
    const int c = 64 * wv + lane;
    float acc[SPB4];
    float cb = c1[c];
#pragma unroll
    for (int s = 0; s < SPB4; ++s) acc[s] = cb;
    const float* wp = V1 + (size_t)64 * 256 + c;
#pragma unroll 4
    for (int m = 0; m < 16; ++m) {
      int k0 = 4 * m;
      float w0 = wp[(k0 + 0) * 256];
      float w1 = wp[(k0 + 1) * 256];
      float w2 = wp[(k0 + 2) * 256];
      float w3 = wp[(k0 + 3) * 256];
#pragma unroll
      for (int s = 0; s < SPB4; ++s) {
        float4 x = *(float4*)&sB[s * 64 + k0];
        acc[s] += x.x * w0 + x.y * w1 + x.z * w2 + x.w * w3;
      }
    }
#pragma unroll
    for (int s = 0; s < SPB4; ++s) sA[s * 256 + c] = siluf(acc[s]);
  }
  __syncthreads();
  {
    const int c = 64 * wv + lane;
    float acc[SPB4];
    float cb = c2[c];
#pragma unroll
    for (int s = 0; s < SPB4; ++s) acc[s] = cb;
    const float* wp = V2 + c;
#pragma unroll 4
    for (int m = 0; m < 64; ++m) {
      int k0 = 4 * m;
      float w0 = wp[(size_t)(k0 + 0) * 256];
      float w1 = wp[(size_t)(k0 + 1) * 256];
      float w2 = wp[(size_t)(k0 + 2) * 256];
      float w3 = wp[(size_t)(k0 + 3) * 256];
#pragma unroll
      for (int s = 0; s < SPB4; ++s) {
        float4 x = *(float4*)&sA[s * 256 + k0];
        acc[s] += x.x * w0 + x.y * w1 + x.z * w2 + x.w * w3;
      }
    }
#pragma unroll
    for (int s = 0; s < SPB4; ++s) sB[s * 256 + c] = siluf(acc[s]);
  }
  __syncthreads();
  {
    float acc[SPB4] = {};
    const int kb = 64 * wv;
#pragma unroll 4
    for (int m = 0; m < 16; ++m) {
      int k0 = kb + 4 * m;
      float w0 = V3[(k0 + 0) * 64 + lane];
      float w1 = V3[(k0 + 1) * 64 + lane];
      float w2 = V3[(k0 + 2) * 64 + lane];
      float w3 = V3[(k0 + 3) * 64 + lane];
#pragma unroll
      for (int s = 0; s < SPB4; ++s) {
        float4 x = *(float4*)&sB[s * 256 + k0];
        acc[s] += x.x * w0 + x.y * w1 + x.z * w2 + x.w * w3;
      }
    }
#pragma unroll
    for (int s = 0; s < SPB4; ++s) sP[wv * 256 + s * 64 + lane] = acc[s];
  }
  __syncthreads();
  {
    int b = bbase + wv;
    float blv = c3[lane] + sP[wv * 64 + lane] + sP[256 + wv * 64 + lane]
              + sP[512 + wv * 64 + lane] + sP[768 + wv * 64 + lane];
    float eb = expf(blv);
    float Zb = waveSum(eb);
    float lp = selectAndPL(blv, eb, Zb, ub + (size_t)b * 64,
                           out + (size_t)b * 128 + 64, lane, nullptr);
    if (lane == 0)
      out[(size_t)8192 * 128 + b] = sLpA[wv] + lp;
  }
}

extern "C" void kernel_launch(void* const* d_in, const int* in_sizes, int n_in,
                              void* d_out, int out_size, void* d_ws, size_t ws_size,
                              hipStream_t stream) {
  const float* ua   = (const float*)d_in[0];
  const float* ub   = (const float*)d_in[1];
  const float* alog = (const float*)d_in[2];
  const float* W1   = (const float*)d_in[3];
  const float* b1   = (const float*)d_in[4];
  const float* W2   = (const float*)d_in[5];
  const float* b2   = (const float*)d_in[6];
  const float* V1   = (const float*)d_in[7];
  const float* c1   = (const float*)d_in[8];
  const float* V2   = (const float*)d_in[9];
  const float* c2   = (const float*)d_in[10];
  const float* V3   = (const float*)d_in[11];
  const float* c3   = (const float*)d_in[12];
  float* out = (float*)d_out;

  if (ws_size >= (size_t)WS_USHORTS * 2) {
    unsigned short* wt = (unsigned short*)d_ws;
    pcf_prep<<<dim3(52), dim3(NTH), 0, stream>>>(W2, V1, V2, V3, wt);
    pcf_mfma<<<dim3(8192 / SPB), dim3(NTH), 0, stream>>>(
        ua, ub, alog, W1, b1, b2, c1, c2, c3, wt, out);
  } else {
    pcf_small<<<dim3(8192 / SPB4), dim3(NTH), 0, stream>>>(
        ua, ub, alog, W1, b1, W2, b2, V1, c1, V2, c2, V3, c3, out);
  }
}

// Round 8
// 112.681 us; speedup vs baseline: 1.9052x; 1.0466x over previous
//
#include <hip/hip_runtime.h>
#include <math.h>

#define NTH 512                     // 8 waves per block
#define KP 264                      // LDS row stride (ushorts), padded
#define SPB 8                       // samples per block
#define OFF_W2 0                    // 4 tiles x 4 ksteps
#define OFF_V1 16384                // 16 x 2
#define OFF_V2 49152                // 16 x 8
#define OFF_V3 180224               // 4 x 8
#define WS_USHORTS 212992
#define MFMA16 __builtin_amdgcn_mfma_f32_16x16x32_bf16

typedef __attribute__((ext_vector_type(8))) short s16x8;
typedef __attribute__((ext_vector_type(8))) unsigned short u16x8;
typedef __attribute__((ext_vector_type(4))) float f32x4;

__device__ __forceinline__ float waveSum(float v) {
#pragma unroll
  for (int off = 32; off; off >>= 1) v += __shfl_xor(v, off, 64);
  return v;
}

__device__ __forceinline__ float siluf(float x) { return x / (1.0f + expf(-x)); }

// Round fp32 -> bf16 (RNE), return bits.
__device__ __forceinline__ unsigned short bround(float x) {
  unsigned u = __float_as_uint(x);
  return (unsigned short)((u + 0x7FFFu + ((u >> 16) & 1u)) >> 16);
}

// Split fp32 into bf16 hi + bf16 lo (round-to-nearest-even).
__device__ __forceinline__ void bsplit(float x, unsigned short& h, unsigned short& l) {
  unsigned u = __float_as_uint(x);
  unsigned hb = (u + 0x7FFFu + ((u >> 16) & 1u)) >> 16;
  float hf = __uint_as_float(hb << 16);
  float lf = x - hf;
  unsigned ul = __float_as_uint(lf);
  unsigned lb = (ul + 0x7FFFu + ((ul >> 16) & 1u)) >> 16;
  h = (unsigned short)hb; l = (unsigned short)lb;
}

__device__ __forceinline__ float permSum(const float se0, const float se1,
                                         const float se2, const float se3,
                                         const float se4, float Z, int lane) {
  float psum = 0.0f;
#pragma unroll
  for (int pp = 0; pp < 2; ++pp) {
    int p = lane + pp * 64;
    if (p < 120) {
      int rem = p;
      unsigned avail = 0x43210u;
      float c = 0.0f;
      float prod = Z;
#pragma unroll
      for (int j = 0; j < 4; ++j) {
        const int fct = (j == 0) ? 24 : (j == 1) ? 6 : (j == 2) ? 2 : 1;
        int q = rem / fct; rem -= q * fct;
        int sh = q * 4;
        int dg = (avail >> sh) & 0xF;
        avail = (avail & ((1u << sh) - 1u)) | ((avail >> (sh + 4)) << sh);
        float ev = (dg == 0) ? se0 : (dg == 1) ? se1 : (dg == 2) ? se2
                 : (dg == 3) ? se3 : se4;
        c += ev;
        prod *= (Z - c);
      }
      psum += 1.0f / prod;
    }
  }
  return psum;
}

__device__ __forceinline__ float selectAndPL(float lv, float ev, float Z,
                                             const float* __restrict__ u64,
                                             float* __restrict__ gout,
                                             int lane, int* sel_i_out) {
  float u = u64[lane];
  float g = -logf(-logf(fmaxf(u, 1e-10f)));
  float vcur = lv + g;
  float sel_e[5];
#pragma unroll
  for (int r = 0; r < 5; ++r) {
    float bv = vcur; int bi = lane;
#pragma unroll
    for (int off = 32; off; off >>= 1) {
      float ov = __shfl_xor(bv, off, 64);
      int   oi = __shfl_xor(bi, off, 64);
      if (ov > bv || (ov == bv && oi < bi)) { bv = ov; bi = oi; }
    }
    if (sel_i_out) sel_i_out[r] = bi;
    sel_e[r] = __shfl(ev, bi, 64);
    if (lane == bi) vcur = -INFINITY;
  }
  float isSel = (vcur == -INFINITY) ? 1.0f : 0.0f;
  gout[lane] = isSel;
  float sl = waveSum(isSel != 0.0f ? lv : 0.0f);
  float S  = waveSum(permSum(sel_e[0], sel_e[1], sel_e[2], sel_e[3],
                             sel_e[4], Z, lane));
  return sl + logf(S);
}

//============ Prep: tile + split weights into fragment order ============
// Layout per matrix: for (ct, ks): 1KB hi block [lane][8] then 1KB lo block.
// Fragment element: n = ct*16 + (lane&15), k = ks*32 + (lane>>4)*8 + j.
__global__ __launch_bounds__(256)
void pcf_prep(const float* __restrict__ W2, const float* __restrict__ V1,
              const float* __restrict__ V2, const float* __restrict__ V3,
              unsigned short* __restrict__ ws)
{
  int tid = blockIdx.x * 256 + threadIdx.x;
  const float* src; int N, Ks, dstoff, r;
  if (tid < 1024)       { src = W2;            N = 64;  Ks = 4; dstoff = OFF_W2; r = tid; }
  else if (tid < 3072)  { src = V1 + 64 * 256; N = 256; Ks = 2; dstoff = OFF_V1; r = tid - 1024; }
  else if (tid < 11264) { src = V2;            N = 256; Ks = 8; dstoff = OFF_V2; r = tid - 3072; }
  else                  { src = V3;            N = 64;  Ks = 8; dstoff = OFF_V3; r = tid - 11264; }
  int lane = r & 63, ts = r >> 6;
  int ks = ts % Ks, ct = ts / Ks;
  int n = ct * 16 + (lane & 15);
  int k0 = ks * 32 + (lane >> 4) * 8;
  u16x8 hv, lv;
#pragma unroll
  for (int j = 0; j < 8; ++j) {
    float x = src[(size_t)(k0 + j) * N + n];
    unsigned short h, l;
    bsplit(x, h, l);
    hv[j] = h; lv[j] = l;
  }
  unsigned short* dst = ws + dstoff + (size_t)ts * 1024 + lane * 8;
  *(u16x8*)dst = hv;
  *(u16x8*)(dst + 512) = lv;
}

//============ Main: 8 samples/block, 8 waves, MFMA (act hi, wt hi+lo) =====
// M rows 8..15 of the MFMA tiles carry garbage; they only ever feed dead
// C rows and dead LDS rows (tile arrays are 16 rows tall), never outputs.
__global__ __launch_bounds__(NTH, 8)
void pcf_mfma(const float* __restrict__ ua, const float* __restrict__ ub,
              const float* __restrict__ alog, const float* __restrict__ W1,
              const float* __restrict__ b1, const float* __restrict__ b2,
              const float* __restrict__ c1, const float* __restrict__ c2,
              const float* __restrict__ c3,
              const unsigned short* __restrict__ wt, float* __restrict__ out)
{
  __shared__ unsigned short sAhi[16 * KP];   // 8448 B
  __shared__ unsigned short sBhi[16 * KP];   // 8448 B
  __shared__ float sBL[SPB * 64];            // 2048 B
  __shared__ int   sSelA[SPB * 5];
  __shared__ float sLpA[SPB];

  const int t    = threadIdx.x;
  const int lane = t & 63;
  const int wv   = t >> 6;                   // 0..7
  const int ln15 = lane & 15;
  const int quad = lane >> 4;
  const int bbase = blockIdx.x * SPB;

  //===== Phase A: alpha top-5 + PL (1 sample per wave) =====
  {
    float la = alog[lane];
    float ea = expf(la);
    float Za = waveSum(ea);
    int b = bbase + wv;
    int sel_i[5];
    float lp = selectAndPL(la, ea, Za, ua + (size_t)b * 64,
                           out + (size_t)b * 128, lane, sel_i);
    if (lane == 0) {
      sLpA[wv] = lp;
#pragma unroll
      for (int r = 0; r < 5; ++r) sSelA[wv * 5 + r] = sel_i[r];
    }
  }
  __syncthreads();

  //===== Phase H: h[s][0..127] = silu(b1 + sum 5 W1 rows) -> sAhi =====
  {
    int s = wv;                 // sample = wave
    int j = lane * 2;           // cols j, j+1
    const int rows[5] = { sSelA[s * 5 + 0], sSelA[s * 5 + 1], sSelA[s * 5 + 2],
                          sSelA[s * 5 + 3], sSelA[s * 5 + 4] };
    float2 a = *(const float2*)(b1 + j);
#pragma unroll
    for (int r = 0; r < 5; ++r) {
      float2 w = *(const float2*)(W1 + (size_t)rows[r] * 128 + j);
      a.x += w.x; a.y += w.y;
    }
    unsigned h0 = bround(siluf(a.x));
    unsigned h1 = bround(siluf(a.y));
    *(unsigned*)&sAhi[s * KP + j] = h0 | (h1 << 16);
  }
  __syncthreads();

  //===== GEMM1: ctx(8x64) = h @ W2 + b2  (K=128, waves 0-3) =====
  if (wv < 4) {
    f32x4 acc = {0.f, 0.f, 0.f, 0.f};
#pragma unroll
    for (int ks = 0; ks < 4; ++ks) {
      int ko = ks * 32 + quad * 8;
      s16x8 ah = *(const s16x8*)&sAhi[ln15 * KP + ko];
      const unsigned short* tsb = wt + OFF_W2 + (size_t)(wv * 4 + ks) * 1024;
      s16x8 bh = ((const s16x8*)tsb)[lane];
      s16x8 bl = ((const s16x8*)(tsb + 512))[lane];
      acc = MFMA16(ah, bh, acc, 0, 0, 0);
      acc = MFMA16(ah, bl, acc, 0, 0, 0);
    }
    int col = wv * 16 + ln15;
    float bias = b2[col];
#pragma unroll
    for (int r = 0; r < 4; ++r)
      sBhi[(quad * 4 + r) * KP + col] = bround(acc[r] + bias);
  }
  __syncthreads();

  //===== GEMM2: z1(8x256) = silu(ctx @ V1[64:,:] + c1)  (K=64, 2 tiles/wave) =====
  {
    f32x4 acc[2];
#pragma unroll
    for (int i = 0; i < 2; ++i) acc[i] = (f32x4){0.f, 0.f, 0.f, 0.f};
#pragma unroll
    for (int ks = 0; ks < 2; ++ks) {
      int ko = ks * 32 + quad * 8;
      s16x8 ah = *(const s16x8*)&sBhi[ln15 * KP + ko];
#pragma unroll
      for (int i = 0; i < 2; ++i) {
        const unsigned short* tsb = wt + OFF_V1 + (size_t)((wv * 2 + i) * 2 + ks) * 1024;
        s16x8 bh = ((const s16x8*)tsb)[lane];
        s16x8 bl = ((const s16x8*)(tsb + 512))[lane];
        acc[i] = MFMA16(ah, bh, acc[i], 0, 0, 0);
        acc[i] = MFMA16(ah, bl, acc[i], 0, 0, 0);
      }
    }
#pragma unroll
    for (int i = 0; i < 2; ++i) {
      int col = (wv * 2 + i) * 16 + ln15;
      float bias = c1[col];
#pragma unroll
      for (int r = 0; r < 4; ++r)
        sAhi[(quad * 4 + r) * KP + col] = bround(siluf(acc[i][r] + bias));
    }
  }
  __syncthreads();

  //===== GEMM3: z2(8x256) = silu(z1 @ V2 + c2)  (K=256, 2 tiles/wave) =====
  {
    f32x4 acc[2];
#pragma unroll
    for (int i = 0; i < 2; ++i) acc[i] = (f32x4){0.f, 0.f, 0.f, 0.f};
#pragma unroll 2
    for (int ks = 0; ks < 8; ++ks) {
      int ko = ks * 32 + quad * 8;
      s16x8 ah = *(const s16x8*)&sAhi[ln15 * KP + ko];
#pragma unroll
      for (int i = 0; i < 2; ++i) {
        const unsigned short* tsb = wt + OFF_V2 + (size_t)((wv * 2 + i) * 8 + ks) * 1024;
        s16x8 bh = ((const s16x8*)tsb)[lane];
        s16x8 bl = ((const s16x8*)(tsb + 512))[lane];
        acc[i] = MFMA16(ah, bh, acc[i], 0, 0, 0);
        acc[i] = MFMA16(ah, bl, acc[i], 0, 0, 0);
      }
    }
#pragma unroll
    for (int i = 0; i < 2; ++i) {
      int col = (wv * 2 + i) * 16 + ln15;
      float bias = c2[col];
#pragma unroll
      for (int r = 0; r < 4; ++r)
        sBhi[(quad * 4 + r) * KP + col] = bround(siluf(acc[i][r] + bias));
    }
  }
  __syncthreads();

  //===== GEMM4: beta_logits(8x64) = z2 @ V3 + c3  (K=256, waves 0-3) =====
  if (wv < 4) {
    f32x4 acc = {0.f, 0.f, 0.f, 0.f};
#pragma unroll
    for (int ks = 0; ks < 8; ++ks) {
      int ko = ks * 32 + quad * 8;
      s16x8 ah = *(const s16x8*)&sBhi[ln15 * KP + ko];
      const unsigned short* tsb = wt + OFF_V3 + (size_t)(wv * 8 + ks) * 1024;
      s16x8 bh = ((const s16x8*)tsb)[lane];
      s16x8 bl = ((const s16x8*)(tsb + 512))[lane];
      acc = MFMA16(ah, bh, acc, 0, 0, 0);
      acc = MFMA16(ah, bl, acc, 0, 0, 0);
    }
    if (quad < 2) {                          // rows 0..7 live, 8..15 dead
      int col = wv * 16 + ln15;
      float bias = c3[col];
#pragma unroll
      for (int r = 0; r < 4; ++r)
        sBL[(quad * 4 + r) * 64 + col] = acc[r] + bias;
    }
  }
  __syncthreads();

  //===== Phase B: beta top-5 + PL (1 sample per wave) =====
  {
    int b = bbase + wv;
    float blv = sBL[wv * 64 + lane];
    float eb = expf(blv);
    float Zb = waveSum(eb);
    float lp = selectAndPL(blv, eb, Zb, ub + (size_t)b * 64,
                           out + (size_t)b * 128 + 64, lane, nullptr);
    if (lane == 0)
      out[(size_t)8192 * 128 + b] = sLpA[wv] + lp;
  }
}

//================= Fallback (R4 kernel, no ws needed) =================
#define SPB4 4
__global__ __launch_bounds__(256, 8)
void pcf_small(const float* __restrict__ ua, const float* __restrict__ ub,
               const float* __restrict__ alog, const float* __restrict__ W1,
               const float* __restrict__ b1, const float* __restrict__ W2,
               const float* __restrict__ b2, const float* __restrict__ V1,
               const float* __restrict__ c1, const float* __restrict__ V2,
               const float* __restrict__ c2, const float* __restrict__ V3,
               const float* __restrict__ c3, float* __restrict__ out)
{
  __shared__ float sA[SPB4 * 256];
  __shared__ float sB[SPB4 * 256];
  __shared__ float sP[4 * 256];
  __shared__ int   sSelA[SPB4 * 5];
  __shared__ float sLpA[SPB4];

  const int t    = threadIdx.x;
  const int lane = t & 63;
  const int wv   = t >> 6;
  const int bbase = blockIdx.x * SPB4;

  {
    float la = alog[lane];
    float ea = expf(la);
    float Za = waveSum(ea);
    int b = bbase + wv;
    int sel_i[5];
    float lp = selectAndPL(la, ea, Za, ua + (size_t)b * 64,
                           out + (size_t)b * 128, lane, sel_i);
    if (lane == 0) {
      sLpA[wv] = lp;
#pragma unroll
      for (int r = 0; r < 5; ++r) sSelA[wv * 5 + r] = sel_i[r];
    }
  }
  __syncthreads();
  {
    int s = wv;
    int i0 = sSelA[s * 5 + 0], i1 = sSelA[s * 5 + 1], i2 = sSelA[s * 5 + 2];
    int i3 = sSelA[s * 5 + 3], i4 = sSelA[s * 5 + 4];
#pragma unroll
    for (int jh = 0; jh < 2; ++jh) {
      int j = lane + jh * 64;
      float acc = b1[j] + W1[i0 * 128 + j] + W1[i1 * 128 + j]
                + W1[i2 * 128 + j] + W1[i3 * 128 + j] + W1[i4 * 128 + j];
      sA[s * 128 + j] = siluf(acc);
    }
  }
  __syncthreads();
  {
    float acc[SPB4] = {};
    const int kb = 32 * wv;
#pragma unroll 2
    for (int m = 0; m < 8; ++m) {
      int k0 = kb + 4 * m;
      float w0 = W2[(k0 + 0) * 64 + lane];
      float w1 = W2[(k0 + 1) * 64 + lane];
      float w2 = W2[(k0 + 2) * 64 + lane];
      float w3 = W2[(k0 + 3) * 64 + lane];
#pragma unroll
      for (int s = 0; s < SPB4; ++s) {
        float4 x = *(float4*)&sA[s * 128 + k0];
        acc[s] += x.x * w0 + x.y * w1 + x.z * w2 + x.w * w3;
      }
    }
#pragma unroll
    for (int s = 0; s < SPB4; ++s) sP[wv * 256 + s * 64 + lane] = acc[s];
  }
  __syncthreads();
  {
    int o = t;
    float v = b2[o & 63] + sP[o] + sP[256 + o] + sP[512 + o] + sP[768 + o];
    sB[o] = v;
  }
  __syncthreads();
  {
    const int c = 64 * wv + lane;
    float acc[SPB4];
    float cb = c1[c];
#pragma unroll
    for (int s = 0; s < SPB4; ++s) acc[s] = cb;
    const float* wp = V1 + (size_t)64 * 256 + c;
#pragma unroll 4
    for (int m = 0; m < 16; ++m) {
      int k0 = 4 * m;
      float w0 = wp[(k0 + 0) * 256];
      float w1 = wp[(k0 + 1) * 256];
      float w2 = wp[(k0 + 2) * 256];
      float w3 = wp[(k0 + 3) * 256];
#pragma unroll
      for (int s = 0; s < SPB4; ++s) {
        float4 x = *(float4*)&sB[s * 64 + k0];
        acc[s] += x.x * w0 + x.y * w1 + x.z * w2 + x.w * w3;
      }
    }
#pragma unroll
    for (int s = 0; s < SPB4; ++s) sA[s * 256 + c] = siluf(acc[s]);
  }
  __syncthreads();
  {
    const int c = 64 * wv + lane;
    float acc[SPB4];
    float cb = c2[c];
#pragma unroll
    for (int s = 0; s < SPB4; ++s) acc[s] = cb;
    const float* wp = V2 + c;
#pragma unroll 4
    for (int m = 0; m < 64; ++m) {
      int k0 = 4 * m;
      float w0 = wp[(size_t)(k0 + 0) * 256];
      float w1 = wp[(size_t)(k0 + 1) * 256];
      float w2 = wp[(size_t)(k0 + 2) * 256];
      float w3 = wp[(size_t)(k0 + 3) * 256];
#pragma unroll
      for (int s = 0; s < SPB4; ++s) {
        float4 x = *(float4*)&sA[s * 256 + k0];
        acc[s] += x.x * w0 + x.y * w1 + x.z * w2 + x.w * w3;
      }
    }
#pragma unroll
    for (int s = 0; s < SPB4; ++s) sB[s * 256 + c] = siluf(acc[s]);
  }
  __syncthreads();
  {
    float acc[SPB4] = {};
    const int kb = 64 * wv;
#pragma unroll 4
    for (int m = 0; m < 16; ++m) {
      int k0 = kb + 4 * m;
      float w0 = V3[(k0 + 0) * 64 + lane];
      float w1 = V3[(k0 + 1) * 64 + lane];
      float w2 = V3[(k0 + 2) * 64 + lane];
      float w3 = V3[(k0 + 3) * 64 + lane];
#pragma unroll
      for (int s = 0; s < SPB4; ++s) {
        float4 x = *(float4*)&sB[s * 256 + k0];
        acc[s] += x.x * w0 + x.y * w1 + x.z * w2 + x.w * w3;
      }
    }
#pragma unroll
    for (int s = 0; s < SPB4; ++s) sP[wv * 256 + s * 64 + lane] = acc[s];
  }
  __syncthreads();
  {
    int b = bbase + wv;
    float blv = c3[lane] + sP[wv * 64 + lane] + sP[256 + wv * 64 + lane]
              + sP[512 + wv * 64 + lane] + sP[768 + wv * 64 + lane];
    float eb = expf(blv);
    float Zb = waveSum(eb);
    float lp = selectAndPL(blv, eb, Zb, ub + (size_t)b * 64,
                           out + (size_t)b * 128 + 64, lane, nullptr);
    if (lane == 0)
      out[(size_t)8192 * 128 + b] = sLpA[wv] + lp;
  }
}

extern "C" void kernel_launch(void* const* d_in, const int* in_sizes, int n_in,
                              void* d_out, int out_size, void* d_ws, size_t ws_size,
                              hipStream_t stream) {
  const float* ua   = (const float*)d_in[0];
  const float* ub   = (const float*)d_in[1];
  const float* alog = (const float*)d_in[2];
  const float* W1   = (const float*)d_in[3];
  const float* b1   = (const float*)d_in[4];
  const float* W2   = (const float*)d_in[5];
  const float* b2   = (const float*)d_in[6];
  const float* V1   = (const float*)d_in[7];
  const float* c1   = (const float*)d_in[8];
  const float* V2   = (const float*)d_in[9];
  const float* c2   = (const float*)d_in[10];
  const float* V3   = (const float*)d_in[11];
  const float* c3   = (const float*)d_in[12];
  float* out = (float*)d_out;

  if (ws_size >= (size_t)WS_USHORTS * 2) {
    unsigned short* wt = (unsigned short*)d_ws;
    pcf_prep<<<dim3(52), dim3(256), 0, stream>>>(W2, V1, V2, V3, wt);
    pcf_mfma<<<dim3(8192 / SPB), dim3(NTH), 0, stream>>>(
        ua, ub, alog, W1, b1, b2, c1, c2, c3, wt, out);
  } else {
    pcf_small<<<dim3(8192 / SPB4), dim3(256), 0, stream>>>(
        ua, ub, alog, W1, b1, W2, b2, V1, c1, V2, c2, V3, c3, out);
  }
}

// Round 9
// 109.349 us; speedup vs baseline: 1.9633x; 1.0305x over previous
//
#include <hip/hip_runtime.h>
#include <math.h>

#define NTH 1024                    // 16 waves per block
#define KP 264                      // LDS row stride (ushorts), padded
#define SPB 16                      // samples per block (fills M=16 MFMA tiles)
#define OFF_W2 0                    // 4 tiles x 4 ksteps
#define OFF_V1 16384                // 16 x 2
#define OFF_V2 49152                // 16 x 8
#define OFF_V3 180224               // 4 x 8
#define WS_USHORTS 212992
#define MFMA16 __builtin_amdgcn_mfma_f32_16x16x32_bf16

typedef __attribute__((ext_vector_type(8))) short s16x8;
typedef __attribute__((ext_vector_type(8))) unsigned short u16x8;
typedef __attribute__((ext_vector_type(4))) float f32x4;

__device__ __forceinline__ float waveSum(float v) {
#pragma unroll
  for (int off = 32; off; off >>= 1) v += __shfl_xor(v, off, 64);
  return v;
}

__device__ __forceinline__ float siluf(float x) { return x / (1.0f + expf(-x)); }

// Round fp32 -> bf16 (RNE), return bits.
__device__ __forceinline__ unsigned short bround(float x) {
  unsigned u = __float_as_uint(x);
  return (unsigned short)((u + 0x7FFFu + ((u >> 16) & 1u)) >> 16);
}

// Split fp32 into bf16 hi + bf16 lo (round-to-nearest-even).
__device__ __forceinline__ void bsplit(float x, unsigned short& h, unsigned short& l) {
  unsigned u = __float_as_uint(x);
  unsigned hb = (u + 0x7FFFu + ((u >> 16) & 1u)) >> 16;
  float hf = __uint_as_float(hb << 16);
  float lf = x - hf;
  unsigned ul = __float_as_uint(lf);
  unsigned lb = (ul + 0x7FFFu + ((ul >> 16) & 1u)) >> 16;
  h = (unsigned short)hb; l = (unsigned short)lb;
}

__device__ __forceinline__ float permSum(const float se0, const float se1,
                                         const float se2, const float se3,
                                         const float se4, float Z, int lane) {
  float psum = 0.0f;
#pragma unroll
  for (int pp = 0; pp < 2; ++pp) {
    int p = lane + pp * 64;
    if (p < 120) {
      int rem = p;
      unsigned avail = 0x43210u;
      float c = 0.0f;
      float prod = Z;
#pragma unroll
      for (int j = 0; j < 4; ++j) {
        const int fct = (j == 0) ? 24 : (j == 1) ? 6 : (j == 2) ? 2 : 1;
        int q = rem / fct; rem -= q * fct;
        int sh = q * 4;
        int dg = (avail >> sh) & 0xF;
        avail = (avail & ((1u << sh) - 1u)) | ((avail >> (sh + 4)) << sh);
        float ev = (dg == 0) ? se0 : (dg == 1) ? se1 : (dg == 2) ? se2
                 : (dg == 3) ? se3 : se4;
        c += ev;
        prod *= (Z - c);
      }
      psum += 1.0f / prod;
    }
  }
  return psum;
}

__device__ __forceinline__ float selectAndPL(float lv, float ev, float Z,
                                             const float* __restrict__ u64,
                                             float* __restrict__ gout,
                                             int lane, int* sel_i_out) {
  float u = u64[lane];
  float g = -logf(-logf(fmaxf(u, 1e-10f)));
  float vcur = lv + g;
  float sel_e[5];
#pragma unroll
  for (int r = 0; r < 5; ++r) {
    float bv = vcur; int bi = lane;
#pragma unroll
    for (int off = 32; off; off >>= 1) {
      float ov = __shfl_xor(bv, off, 64);
      int   oi = __shfl_xor(bi, off, 64);
      if (ov > bv || (ov == bv && oi < bi)) { bv = ov; bi = oi; }
    }
    if (sel_i_out) sel_i_out[r] = bi;
    sel_e[r] = __shfl(ev, bi, 64);
    if (lane == bi) vcur = -INFINITY;
  }
  float isSel = (vcur == -INFINITY) ? 1.0f : 0.0f;
  gout[lane] = isSel;
  float sl = waveSum(isSel != 0.0f ? lv : 0.0f);
  float S  = waveSum(permSum(sel_e[0], sel_e[1], sel_e[2], sel_e[3],
                             sel_e[4], Z, lane));
  return sl + logf(S);
}

//============ Prep: tile + split weights into fragment order ============
// Layout per matrix: for (ct, ks): 1KB hi block [lane][8] then 1KB lo block.
// Fragment element: n = ct*16 + (lane&15), k = ks*32 + (lane>>4)*8 + j.
__global__ __launch_bounds__(256)
void pcf_prep(const float* __restrict__ W2, const float* __restrict__ V1,
              const float* __restrict__ V2, const float* __restrict__ V3,
              unsigned short* __restrict__ ws)
{
  int tid = blockIdx.x * 256 + threadIdx.x;
  const float* src; int N, Ks, dstoff, r;
  if (tid < 1024)       { src = W2;            N = 64;  Ks = 4; dstoff = OFF_W2; r = tid; }
  else if (tid < 3072)  { src = V1 + 64 * 256; N = 256; Ks = 2; dstoff = OFF_V1; r = tid - 1024; }
  else if (tid < 11264) { src = V2;            N = 256; Ks = 8; dstoff = OFF_V2; r = tid - 3072; }
  else                  { src = V3;            N = 64;  Ks = 8; dstoff = OFF_V3; r = tid - 11264; }
  int lane = r & 63, ts = r >> 6;
  int ks = ts % Ks, ct = ts / Ks;
  int n = ct * 16 + (lane & 15);
  int k0 = ks * 32 + (lane >> 4) * 8;
  u16x8 hv, lv;
#pragma unroll
  for (int j = 0; j < 8; ++j) {
    float x = src[(size_t)(k0 + j) * N + n];
    unsigned short h, l;
    bsplit(x, h, l);
    hv[j] = h; lv[j] = l;
  }
  unsigned short* dst = ws + dstoff + (size_t)ts * 1024 + lane * 8;
  *(u16x8*)dst = hv;
  *(u16x8*)(dst + 512) = lv;
}

//============ Main: 16 samples/block, 16 waves, MFMA (act hi, wt hi+lo) =====
__global__ __launch_bounds__(NTH, 8)
void pcf_mfma(const float* __restrict__ ua, const float* __restrict__ ub,
              const float* __restrict__ alog, const float* __restrict__ W1,
              const float* __restrict__ b1, const float* __restrict__ b2,
              const float* __restrict__ c1, const float* __restrict__ c2,
              const float* __restrict__ c3,
              const unsigned short* __restrict__ wt, float* __restrict__ out)
{
  __shared__ unsigned short sAhi[16 * KP];   // 8448 B
  __shared__ unsigned short sBhi[16 * KP];   // 8448 B
  __shared__ float sBL[SPB * 64];            // 4096 B
  __shared__ int   sSelA[SPB * 5];
  __shared__ float sLpA[SPB];

  const int t    = threadIdx.x;
  const int lane = t & 63;
  const int wv   = t >> 6;                   // 0..15
  const int ln15 = lane & 15;
  const int quad = lane >> 4;
  const int bbase = blockIdx.x * SPB;

  //===== Phase A: alpha top-5 + PL (1 sample per wave) =====
  {
    float la = alog[lane];
    float ea = expf(la);
    float Za = waveSum(ea);
    int b = bbase + wv;
    int sel_i[5];
    float lp = selectAndPL(la, ea, Za, ua + (size_t)b * 64,
                           out + (size_t)b * 128, lane, sel_i);
    if (lane == 0) {
      sLpA[wv] = lp;
#pragma unroll
      for (int r = 0; r < 5; ++r) sSelA[wv * 5 + r] = sel_i[r];
    }
  }
  __syncthreads();

  //===== Phase H: h[s][0..127] = silu(b1 + sum 5 W1 rows) -> sAhi =====
  {
    int s = wv;                 // sample = wave
    int j = lane * 2;           // cols j, j+1
    const int rows[5] = { sSelA[s * 5 + 0], sSelA[s * 5 + 1], sSelA[s * 5 + 2],
                          sSelA[s * 5 + 3], sSelA[s * 5 + 4] };
    float2 a = *(const float2*)(b1 + j);
#pragma unroll
    for (int r = 0; r < 5; ++r) {
      float2 w = *(const float2*)(W1 + (size_t)rows[r] * 128 + j);
      a.x += w.x; a.y += w.y;
    }
    unsigned h0 = bround(siluf(a.x));
    unsigned h1 = bround(siluf(a.y));
    *(unsigned*)&sAhi[s * KP + j] = h0 | (h1 << 16);
  }
  __syncthreads();

  //===== GEMM1: ctx(16x64) = h @ W2 + b2  (K=128, waves 0-3) =====
  if (wv < 4) {
    f32x4 acc = {0.f, 0.f, 0.f, 0.f};
#pragma unroll
    for (int ks = 0; ks < 4; ++ks) {
      int ko = ks * 32 + quad * 8;
      s16x8 ah = *(const s16x8*)&sAhi[ln15 * KP + ko];
      const unsigned short* tsb = wt + OFF_W2 + (size_t)(wv * 4 + ks) * 1024;
      s16x8 bh = ((const s16x8*)tsb)[lane];
      s16x8 bl = ((const s16x8*)(tsb + 512))[lane];
      acc = MFMA16(ah, bh, acc, 0, 0, 0);
      acc = MFMA16(ah, bl, acc, 0, 0, 0);
    }
    int col = wv * 16 + ln15;
    float bias = b2[col];
#pragma unroll
    for (int r = 0; r < 4; ++r)
      sBhi[(quad * 4 + r) * KP + col] = bround(acc[r] + bias);
  }
  __syncthreads();

  //===== GEMM2: z1(16x256) = silu(ctx @ V1[64:,:] + c1)  (K=64, 1 tile/wave) =====
  {
    f32x4 acc = {0.f, 0.f, 0.f, 0.f};
#pragma unroll
    for (int ks = 0; ks < 2; ++ks) {
      int ko = ks * 32 + quad * 8;
      s16x8 ah = *(const s16x8*)&sBhi[ln15 * KP + ko];
      const unsigned short* tsb = wt + OFF_V1 + (size_t)(wv * 2 + ks) * 1024;
      s16x8 bh = ((const s16x8*)tsb)[lane];
      s16x8 bl = ((const s16x8*)(tsb + 512))[lane];
      acc = MFMA16(ah, bh, acc, 0, 0, 0);
      acc = MFMA16(ah, bl, acc, 0, 0, 0);
    }
    int col = wv * 16 + ln15;
    float bias = c1[col];
#pragma unroll
    for (int r = 0; r < 4; ++r)
      sAhi[(quad * 4 + r) * KP + col] = bround(siluf(acc[r] + bias));
  }
  __syncthreads();

  //===== GEMM3: z2(16x256) = silu(z1 @ V2 + c2)  (K=256, 1 tile/wave) =====
  {
    f32x4 acc = {0.f, 0.f, 0.f, 0.f};
#pragma unroll 2
    for (int ks = 0; ks < 8; ++ks) {
      int ko = ks * 32 + quad * 8;
      s16x8 ah = *(const s16x8*)&sAhi[ln15 * KP + ko];
      const unsigned short* tsb = wt + OFF_V2 + (size_t)(wv * 8 + ks) * 1024;
      s16x8 bh = ((const s16x8*)tsb)[lane];
      s16x8 bl = ((const s16x8*)(tsb + 512))[lane];
      acc = MFMA16(ah, bh, acc, 0, 0, 0);
      acc = MFMA16(ah, bl, acc, 0, 0, 0);
    }
    int col = wv * 16 + ln15;
    float bias = c2[col];
#pragma unroll
    for (int r = 0; r < 4; ++r)
      sBhi[(quad * 4 + r) * KP + col] = bround(siluf(acc[r] + bias));
  }
  __syncthreads();

  //===== GEMM4: beta_logits(16x64) = z2 @ V3 + c3  (K=256, waves 0-3) =====
  if (wv < 4) {
    f32x4 acc = {0.f, 0.f, 0.f, 0.f};
#pragma unroll
    for (int ks = 0; ks < 8; ++ks) {
      int ko = ks * 32 + quad * 8;
      s16x8 ah = *(const s16x8*)&sBhi[ln15 * KP + ko];
      const unsigned short* tsb = wt + OFF_V3 + (size_t)(wv * 8 + ks) * 1024;
      s16x8 bh = ((const s16x8*)tsb)[lane];
      s16x8 bl = ((const s16x8*)(tsb + 512))[lane];
      acc = MFMA16(ah, bh, acc, 0, 0, 0);
      acc = MFMA16(ah, bl, acc, 0, 0, 0);
    }
    int col = wv * 16 + ln15;
    float bias = c3[col];
#pragma unroll
    for (int r = 0; r < 4; ++r)
      sBL[(quad * 4 + r) * 64 + col] = acc[r] + bias;
  }
  __syncthreads();

  //===== Phase B: beta top-5 + PL (1 sample per wave) =====
  {
    int b = bbase + wv;
    float blv = sBL[wv * 64 + lane];
    float eb = expf(blv);
    float Zb = waveSum(eb);
    float lp = selectAndPL(blv, eb, Zb, ub + (size_t)b * 64,
                           out + (size_t)b * 128 + 64, lane, nullptr);
    if (lane == 0)
      out[(size_t)8192 * 128 + b] = sLpA[wv] + lp;
  }
}

//================= Fallback (R4 kernel, no ws needed) =================
#define SPB4 4
__global__ __launch_bounds__(256, 8)
void pcf_small(const float* __restrict__ ua, const float* __restrict__ ub,
               const float* __restrict__ alog, const float* __restrict__ W1,
               const float* __restrict__ b1, const float* __restrict__ W2,
               const float* __restrict__ b2, const float* __restrict__ V1,
               const float* __restrict__ c1, const float* __restrict__ V2,
               const float* __restrict__ c2, const float* __restrict__ V3,
               const float* __restrict__ c3, float* __restrict__ out)
{
  __shared__ float sA[SPB4 * 256];
  __shared__ float sB[SPB4 * 256];
  __shared__ float sP[4 * 256];
  __shared__ int   sSelA[SPB4 * 5];
  __shared__ float sLpA[SPB4];

  const int t    = threadIdx.x;
  const int lane = t & 63;
  const int wv   = t >> 6;
  const int bbase = blockIdx.x * SPB4;

  {
    float la = alog[lane];
    float ea = expf(la);
    float Za = waveSum(ea);
    int b = bbase + wv;
    int sel_i[5];
    float lp = selectAndPL(la, ea, Za, ua + (size_t)b * 64,
                           out + (size_t)b * 128, lane, sel_i);
    if (lane == 0) {
      sLpA[wv] = lp;
#pragma unroll
      for (int r = 0; r < 5; ++r) sSelA[wv * 5 + r] = sel_i[r];
    }
  }
  __syncthreads();
  {
    int s = wv;
    int i0 = sSelA[s * 5 + 0], i1 = sSelA[s * 5 + 1], i2 = sSelA[s * 5 + 2];
    int i3 = sSelA[s * 5 + 3], i4 = sSelA[s * 5 + 4];
#pragma unroll
    for (int jh = 0; jh < 2; ++jh) {
      int j = lane + jh * 64;
      float acc = b1[j] + W1[i0 * 128 + j] + W1[i1 * 128 + j]
                + W1[i2 * 128 + j] + W1[i3 * 128 + j] + W1[i4 * 128 + j];
      sA[s * 128 + j] = siluf(acc);
    }
  }
  __syncthreads();
  {
    float acc[SPB4] = {};
    const int kb = 32 * wv;
#pragma unroll 2
    for (int m = 0; m < 8; ++m) {
      int k0 = kb + 4 * m;
      float w0 = W2[(k0 + 0) * 64 + lane];
      float w1 = W2[(k0 + 1) * 64 + lane];
      float w2 = W2[(k0 + 2) * 64 + lane];
      float w3 = W2[(k0 + 3) * 64 + lane];
#pragma unroll
      for (int s = 0; s < SPB4; ++s) {
        float4 x = *(float4*)&sA[s * 128 + k0];
        acc[s] += x.x * w0 + x.y * w1 + x.z * w2 + x.w * w3;
      }
    }
#pragma unroll
    for (int s = 0; s < SPB4; ++s) sP[wv * 256 + s * 64 + lane] = acc[s];
  }
  __syncthreads();
  {
    int o = t;
    float v = b2[o & 63] + sP[o] + sP[256 + o] + sP[512 + o] + sP[768 + o];
    sB[o] = v;
  }
  __syncthreads();
  {
    const int c = 64 * wv + lane;
    float acc[SPB4];
    float cb = c1[c];
#pragma unroll
    for (int s = 0; s < SPB4; ++s) acc[s] = cb;
    const float* wp = V1 + (size_t)64 * 256 + c;
#pragma unroll 4
    for (int m = 0; m < 16; ++m) {
      int k0 = 4 * m;
      float w0 = wp[(k0 + 0) * 256];
      float w1 = wp[(k0 + 1) * 256];
      float w2 = wp[(k0 + 2) * 256];
      float w3 = wp[(k0 + 3) * 256];
#pragma unroll
      for (int s = 0; s < SPB4; ++s) {
        float4 x = *(float4*)&sB[s * 64 + k0];
        acc[s] += x.x * w0 + x.y * w1 + x.z * w2 + x.w * w3;
      }
    }
#pragma unroll
    for (int s = 0; s < SPB4; ++s) sA[s * 256 + c] = siluf(acc[s]);
  }
  __syncthreads();
  {
    const int c = 64 * wv + lane;
    float acc[SPB4];
    float cb = c2[c];
#pragma unroll
    for (int s = 0; s < SPB4; ++s) acc[s] = cb;
    const float* wp = V2 + c;
#pragma unroll 4
    for (int m = 0; m < 64; ++m) {
      int k0 = 4 * m;
      float w0 = wp[(size_t)(k0 + 0) * 256];
      float w1 = wp[(size_t)(k0 + 1) * 256];
      float w2 = wp[(size_t)(k0 + 2) * 256];
      float w3 = wp[(size_t)(k0 + 3) * 256];
#pragma unroll
      for (int s = 0; s < SPB4; ++s) {
        float4 x = *(float4*)&sA[s * 256 + k0];
        acc[s] += x.x * w0 + x.y * w1 + x.z * w2 + x.w * w3;
      }
    }
#pragma unroll
    for (int s = 0; s < SPB4; ++s) sB[s * 256 + c] = siluf(acc[s]);
  }
  __syncthreads();
  {
    float acc[SPB4] = {};
    const int kb = 64 * wv;
#pragma unroll 4
    for (int m = 0; m < 16; ++m) {
      int k0 = kb + 4 * m;
      float w0 = V3[(k0 + 0) * 64 + lane];
      float w1 = V3[(k0 + 1) * 64 + lane];
      float w2 = V3[(k0 + 2) * 64 + lane];
      float w3 = V3[(k0 + 3) * 64 + lane];
#pragma unroll
      for (int s = 0; s < SPB4; ++s) {
        float4 x = *(float4*)&sB[s * 256 + k0];
        acc[s] += x.x * w0 + x.y * w1 + x.z * w2 + x.w * w3;
      }
    }
#pragma unroll
    for (int s = 0; s < SPB4; ++s) sP[wv * 256 + s * 64 + lane] = acc[s];
  }
  __syncthreads();
  {
    int b = bbase + wv;
    float blv = c3[lane] + sP[wv * 64 + lane] + sP[256 + wv * 64 + lane]
              + sP[512 + wv * 64 + lane] + sP[768 + wv * 64 + lane];
    float eb = expf(blv);
    float Zb = waveSum(eb);
    float lp = selectAndPL(blv, eb, Zb, ub + (size_t)b * 64,
                           out + (size_t)b * 128 + 64, lane, nullptr);
    if (lane == 0)
      out[(size_t)8192 * 128 + b] = sLpA[wv] + lp;
  }
}

extern "C" void kernel_launch(void* const* d_in, const int* in_sizes, int n_in,
                              void* d_out, int out_size, void* d_ws, size_t ws_size,
                              hipStream_t stream) {
  const float* ua   = (const float*)d_in[0];
  const float* ub   = (const float*)d_in[1];
  const float* alog = (const float*)d_in[2];
  const float* W1   = (const float*)d_in[3];
  const float* b1   = (const float*)d_in[4];
  const float* W2   = (const float*)d_in[5];
  const float* b2   = (const float*)d_in[6];
  const float* V1   = (const float*)d_in[7];
  const float* c1   = (const float*)d_in[8];
  const float* V2   = (const float*)d_in[9];
  const float* c2   = (const float*)d_in[10];
  const float* V3   = (const float*)d_in[11];
  const float* c3   = (const float*)d_in[12];
  float* out = (float*)d_out;

  if (ws_size >= (size_t)WS_USHORTS * 2) {
    unsigned short* wt = (unsigned short*)d_ws;
    pcf_prep<<<dim3(52), dim3(256), 0, stream>>>(W2, V1, V2, V3, wt);
    pcf_mfma<<<dim3(8192 / SPB), dim3(NTH), 0, stream>>>(
        ua, ub, alog, W1, b1, b2, c1, c2, c3, wt, out);
  } else {
    pcf_small<<<dim3(8192 / SPB4), dim3(256), 0, stream>>>(
        ua, ub, alog, W1, b1, W2, b2, V1, c1, V2, c2, V3, c3, out);
  }
}

// Round 10
// 108.276 us; speedup vs baseline: 1.9827x; 1.0099x over previous
//
#include <hip/hip_runtime.h>
#include <math.h>

#define NTH 1024                    // 16 waves per block
#define KP 264                      // LDS row stride (ushorts), padded
#define SPB 16                      // samples per block (fills M=16 MFMA tiles)
#define OFF_W2 0                    // 4 tiles x 4 ksteps
#define OFF_V1 16384                // 16 x 2
#define OFF_V2 49152                // 16 x 8
#define OFF_V3 180224               // 4 x 8
#define WS_USHORTS 212992
#define MFMA16 __builtin_amdgcn_mfma_f32_16x16x32_bf16

typedef __attribute__((ext_vector_type(8))) short s16x8;
typedef __attribute__((ext_vector_type(8))) unsigned short u16x8;
typedef __attribute__((ext_vector_type(4))) float f32x4;

__device__ __forceinline__ float waveSum(float v) {
#pragma unroll
  for (int off = 32; off; off >>= 1) v += __shfl_xor(v, off, 64);
  return v;
}

__device__ __forceinline__ float siluf(float x) { return x / (1.0f + expf(-x)); }

// Round fp32 -> bf16 (RNE), return bits.
__device__ __forceinline__ unsigned short bround(float x) {
  unsigned u = __float_as_uint(x);
  return (unsigned short)((u + 0x7FFFu + ((u >> 16) & 1u)) >> 16);
}

// Split fp32 into bf16 hi + bf16 lo (round-to-nearest-even).
__device__ __forceinline__ void bsplit(float x, unsigned short& h, unsigned short& l) {
  unsigned u = __float_as_uint(x);
  unsigned hb = (u + 0x7FFFu + ((u >> 16) & 1u)) >> 16;
  float hf = __uint_as_float(hb << 16);
  float lf = x - hf;
  unsigned ul = __float_as_uint(lf);
  unsigned lb = (ul + 0x7FFFu + ((ul >> 16) & 1u)) >> 16;
  h = (unsigned short)hb; l = (unsigned short)lb;
}

// permSum is symmetric in (se0..se4): it sums over all 120 orderings, so the
// selected exp-values may be supplied in ANY order.
__device__ __forceinline__ float permSum(const float se0, const float se1,
                                         const float se2, const float se3,
                                         const float se4, float Z, int lane) {
  float psum = 0.0f;
#pragma unroll
  for (int pp = 0; pp < 2; ++pp) {
    int p = lane + pp * 64;
    if (p < 120) {
      int rem = p;
      unsigned avail = 0x43210u;
      float c = 0.0f;
      float prod = Z;
#pragma unroll
      for (int j = 0; j < 4; ++j) {
        const int fct = (j == 0) ? 24 : (j == 1) ? 6 : (j == 2) ? 2 : 1;
        int q = rem / fct; rem -= q * fct;
        int sh = q * 4;
        int dg = (avail >> sh) & 0xF;
        avail = (avail & ((1u << sh) - 1u)) | ((avail >> (sh + 4)) << sh);
        float ev = (dg == 0) ? se0 : (dg == 1) ? se1 : (dg == 2) ? se2
                 : (dg == 3) ? se3 : se4;
        c += ev;
        prod *= (Z - c);
      }
      psum += 1.0f / prod;
    }
  }
  return psum;
}

// Rank-based Gumbel top-5 + exact PL log-prob. Tie-break (v equal -> lower
// index wins) matches jax.lax.top_k. sValsRow/sSelERow are wave-private LDS
// rows (64 floats / 8 floats); same-wave DS ordering makes this barrier-free.
__device__ __forceinline__ float selectAndPL(float lv, float ev, float Z,
                                             const float* __restrict__ u64,
                                             float* __restrict__ gout,
                                             int lane,
                                             float* __restrict__ sValsRow,
                                             float* __restrict__ sSelERow,
                                             int* __restrict__ selIdxRow) {
  float u = u64[lane];
  float g = -logf(-logf(fmaxf(u, 1e-10f)));
  float v = lv + g;
  sValsRow[lane] = v;
  int rank = 0;
#pragma unroll
  for (int j = 0; j < 16; ++j) {
    float4 w = *(const float4*)&sValsRow[j * 4];
    int base = j * 4;
    rank += (w.x > v || (w.x == v && base + 0 < lane)) ? 1 : 0;
    rank += (w.y > v || (w.y == v && base + 1 < lane)) ? 1 : 0;
    rank += (w.z > v || (w.z == v && base + 2 < lane)) ? 1 : 0;
    rank += (w.w > v || (w.w == v && base + 3 < lane)) ? 1 : 0;
  }
  bool sel = rank < 5;
  gout[lane] = sel ? 1.0f : 0.0f;
  if (sel) {
    sSelERow[rank] = ev;
    if (selIdxRow) selIdxRow[rank] = lane;
  }
  float sl = waveSum(sel ? lv : 0.0f);
  float se0 = sSelERow[0], se1 = sSelERow[1], se2 = sSelERow[2],
        se3 = sSelERow[3], se4 = sSelERow[4];
  float S = waveSum(permSum(se0, se1, se2, se3, se4, Z, lane));
  return sl + logf(S);
}

//============ Prep: tile + split weights into fragment order ============
// Layout per matrix: for (ct, ks): 1KB hi block [lane][8] then 1KB lo block.
// Fragment element: n = ct*16 + (lane&15), k = ks*32 + (lane>>4)*8 + j.
__global__ __launch_bounds__(256)
void pcf_prep(const float* __restrict__ W2, const float* __restrict__ V1,
              const float* __restrict__ V2, const float* __restrict__ V3,
              unsigned short* __restrict__ ws)
{
  int tid = blockIdx.x * 256 + threadIdx.x;
  const float* src; int N, Ks, dstoff, r;
  if (tid < 1024)       { src = W2;            N = 64;  Ks = 4; dstoff = OFF_W2; r = tid; }
  else if (tid < 3072)  { src = V1 + 64 * 256; N = 256; Ks = 2; dstoff = OFF_V1; r = tid - 1024; }
  else if (tid < 11264) { src = V2;            N = 256; Ks = 8; dstoff = OFF_V2; r = tid - 3072; }
  else                  { src = V3;            N = 64;  Ks = 8; dstoff = OFF_V3; r = tid - 11264; }
  int lane = r & 63, ts = r >> 6;
  int ks = ts % Ks, ct = ts / Ks;
  int n = ct * 16 + (lane & 15);
  int k0 = ks * 32 + (lane >> 4) * 8;
  u16x8 hv, lv;
#pragma unroll
  for (int j = 0; j < 8; ++j) {
    float x = src[(size_t)(k0 + j) * N + n];
    unsigned short h, l;
    bsplit(x, h, l);
    hv[j] = h; lv[j] = l;
  }
  unsigned short* dst = ws + dstoff + (size_t)ts * 1024 + lane * 8;
  *(u16x8*)dst = hv;
  *(u16x8*)(dst + 512) = lv;
}

//============ Main: 16 samples/block, 16 waves, MFMA (act hi, wt hi+lo) =====
__global__ __launch_bounds__(NTH, 8)
void pcf_mfma(const float* __restrict__ ua, const float* __restrict__ ub,
              const float* __restrict__ alog, const float* __restrict__ W1,
              const float* __restrict__ b1, const float* __restrict__ b2,
              const float* __restrict__ c1, const float* __restrict__ c2,
              const float* __restrict__ c3,
              const unsigned short* __restrict__ wt, float* __restrict__ out)
{
  __shared__ unsigned short sAhi[16 * KP];   // 8448 B
  __shared__ unsigned short sBhi[16 * KP];   // 8448 B
  __shared__ float sBL[SPB * 64];            // 4096 B
  __shared__ float sVals[16 * 64];           // 4096 B  rank scratch (per wave)
  __shared__ float sSelE[16 * 8];            // 512 B   selected exps (per wave)
  __shared__ int   sSelA[SPB * 5];
  __shared__ float sLpA[SPB];

  const int t    = threadIdx.x;
  const int lane = t & 63;
  const int wv   = t >> 6;                   // 0..15
  const int ln15 = lane & 15;
  const int quad = lane >> 4;
  const int bbase = blockIdx.x * SPB;

  float* sValsRow = &sVals[wv * 64];
  float* sSelERow = &sSelE[wv * 8];

  //===== Phase A: alpha top-5 + PL (1 sample per wave) =====
  {
    float la = alog[lane];
    float ea = expf(la);
    float Za = waveSum(ea);
    int b = bbase + wv;
    float lp = selectAndPL(la, ea, Za, ua + (size_t)b * 64,
                           out + (size_t)b * 128, lane,
                           sValsRow, sSelERow, &sSelA[wv * 5]);
    if (lane == 0) sLpA[wv] = lp;
  }
  __syncthreads();

  //===== Phase H: h[s][0..127] = silu(b1 + sum 5 W1 rows) -> sAhi =====
  {
    int s = wv;                 // sample = wave
    int j = lane * 2;           // cols j, j+1
    const int rows[5] = { sSelA[s * 5 + 0], sSelA[s * 5 + 1], sSelA[s * 5 + 2],
                          sSelA[s * 5 + 3], sSelA[s * 5 + 4] };
    float2 a = *(const float2*)(b1 + j);
#pragma unroll
    for (int r = 0; r < 5; ++r) {
      float2 w = *(const float2*)(W1 + (size_t)rows[r] * 128 + j);
      a.x += w.x; a.y += w.y;
    }
    unsigned h0 = bround(siluf(a.x));
    unsigned h1 = bround(siluf(a.y));
    *(unsigned*)&sAhi[s * KP + j] = h0 | (h1 << 16);
  }
  __syncthreads();

  //===== GEMM1: ctx(16x64) = h @ W2 + b2  (K=128, waves 0-3) =====
  if (wv < 4) {
    f32x4 acc = {0.f, 0.f, 0.f, 0.f};
#pragma unroll
    for (int ks = 0; ks < 4; ++ks) {
      int ko = ks * 32 + quad * 8;
      s16x8 ah = *(const s16x8*)&sAhi[ln15 * KP + ko];
      const unsigned short* tsb = wt + OFF_W2 + (size_t)(wv * 4 + ks) * 1024;
      s16x8 bh = ((const s16x8*)tsb)[lane];
      s16x8 bl = ((const s16x8*)(tsb + 512))[lane];
      acc = MFMA16(ah, bh, acc, 0, 0, 0);
      acc = MFMA16(ah, bl, acc, 0, 0, 0);
    }
    int col = wv * 16 + ln15;
    float bias = b2[col];
#pragma unroll
    for (int r = 0; r < 4; ++r)
      sBhi[(quad * 4 + r) * KP + col] = bround(acc[r] + bias);
  }
  __syncthreads();

  //===== GEMM2: z1(16x256) = silu(ctx @ V1[64:,:] + c1)  (K=64, 1 tile/wave) =====
  {
    f32x4 acc = {0.f, 0.f, 0.f, 0.f};
#pragma unroll
    for (int ks = 0; ks < 2; ++ks) {
      int ko = ks * 32 + quad * 8;
      s16x8 ah = *(const s16x8*)&sBhi[ln15 * KP + ko];
      const unsigned short* tsb = wt + OFF_V1 + (size_t)(wv * 2 + ks) * 1024;
      s16x8 bh = ((const s16x8*)tsb)[lane];
      s16x8 bl = ((const s16x8*)(tsb + 512))[lane];
      acc = MFMA16(ah, bh, acc, 0, 0, 0);
      acc = MFMA16(ah, bl, acc, 0, 0, 0);
    }
    int col = wv * 16 + ln15;
    float bias = c1[col];
#pragma unroll
    for (int r = 0; r < 4; ++r)
      sAhi[(quad * 4 + r) * KP + col] = bround(siluf(acc[r] + bias));
  }
  __syncthreads();

  //===== GEMM3: z2(16x256) = silu(z1 @ V2 + c2)  (K=256, 1 tile/wave) =====
  {
    f32x4 acc = {0.f, 0.f, 0.f, 0.f};
#pragma unroll 4
    for (int ks = 0; ks < 8; ++ks) {
      int ko = ks * 32 + quad * 8;
      s16x8 ah = *(const s16x8*)&sAhi[ln15 * KP + ko];
      const unsigned short* tsb = wt + OFF_V2 + (size_t)(wv * 8 + ks) * 1024;
      s16x8 bh = ((const s16x8*)tsb)[lane];
      s16x8 bl = ((const s16x8*)(tsb + 512))[lane];
      acc = MFMA16(ah, bh, acc, 0, 0, 0);
      acc = MFMA16(ah, bl, acc, 0, 0, 0);
    }
    int col = wv * 16 + ln15;
    float bias = c2[col];
#pragma unroll
    for (int r = 0; r < 4; ++r)
      sBhi[(quad * 4 + r) * KP + col] = bround(siluf(acc[r] + bias));
  }
  __syncthreads();

  //===== GEMM4: beta_logits(16x64) = z2 @ V3 + c3  (K=256, waves 0-3) =====
  if (wv < 4) {
    f32x4 acc = {0.f, 0.f, 0.f, 0.f};
#pragma unroll
    for (int ks = 0; ks < 8; ++ks) {
      int ko = ks * 32 + quad * 8;
      s16x8 ah = *(const s16x8*)&sBhi[ln15 * KP + ko];
      const unsigned short* tsb = wt + OFF_V3 + (size_t)(wv * 8 + ks) * 1024;
      s16x8 bh = ((const s16x8*)tsb)[lane];
      s16x8 bl = ((const s16x8*)(tsb + 512))[lane];
      acc = MFMA16(ah, bh, acc, 0, 0, 0);
      acc = MFMA16(ah, bl, acc, 0, 0, 0);
    }
    int col = wv * 16 + ln15;
    float bias = c3[col];
#pragma unroll
    for (int r = 0; r < 4; ++r)
      sBL[(quad * 4 + r) * 64 + col] = acc[r] + bias;
  }
  __syncthreads();

  //===== Phase B: beta top-5 + PL (1 sample per wave) =====
  {
    int b = bbase + wv;
    float blv = sBL[wv * 64 + lane];
    float eb = expf(blv);
    float Zb = waveSum(eb);
    float lp = selectAndPL(blv, eb, Zb, ub + (size_t)b * 64,
                           out + (size_t)b * 128 + 64, lane,
                           sValsRow, sSelERow, nullptr);
    if (lane == 0)
      out[(size_t)8192 * 128 + b] = sLpA[wv] + lp;
  }
}

//================= Fallback (R4-style kernel, no ws needed) =================
#define SPB4 4
__global__ __launch_bounds__(256, 8)
void pcf_small(const float* __restrict__ ua, const float* __restrict__ ub,
               const float* __restrict__ alog, const float* __restrict__ W1,
               const float* __restrict__ b1, const float* __restrict__ W2,
               const float* __restrict__ b2, const float* __restrict__ V1,
               const float* __restrict__ c1, const float* __restrict__ V2,
               const float* __restrict__ c2, const float* __restrict__ V3,
               const float* __restrict__ c3, float* __restrict__ out)
{
  __shared__ float sA[SPB4 * 256];
  __shared__ float sB[SPB4 * 256];
  __shared__ float sP[4 * 256];
  __shared__ float sVals[4 * 64];
  __shared__ float sSelE[4 * 8];
  __shared__ int   sSelA[SPB4 * 5];
  __shared__ float sLpA[SPB4];

  const int t    = threadIdx.x;
  const int lane = t & 63;
  const int wv   = t >> 6;
  const int bbase = blockIdx.x * SPB4;

  float* sValsRow = &sVals[wv * 64];
  float* sSelERow = &sSelE[wv * 8];

  {
    float la = alog[lane];
    float ea = expf(la);
    float Za = waveSum(ea);
    int b = bbase + wv;
    float lp = selectAndPL(la, ea, Za, ua + (size_t)b * 64,
                           out + (size_t)b * 128, lane,
                           sValsRow, sSelERow, &sSelA[wv * 5]);
    if (lane == 0) sLpA[wv] = lp;
  }
  __syncthreads();
  {
    int s = wv;
    int i0 = sSelA[s * 5 + 0], i1 = sSelA[s * 5 + 1], i2 = sSelA[s * 5 + 2];
    int i3 = sSelA[s * 5 + 3], i4 = sSelA[s * 5 + 4];
#pragma unroll
    for (int jh = 0; jh < 2; ++jh) {
      int j = lane + jh * 64;
      float acc = b1[j] + W1[i0 * 128 + j] + W1[i1 * 128 + j]
                + W1[i2 * 128 + j] + W1[i3 * 128 + j] + W1[i4 * 128 + j];
      sA[s * 128 + j] = siluf(acc);
    }
  }
  __syncthreads();
  {
    float acc[SPB4] = {};
    const int kb = 32 * wv;
#pragma unroll 2
    for (int m = 0; m < 8; ++m) {
      int k0 = kb + 4 * m;
      float w0 = W2[(k0 + 0) * 64 + lane];
      float w1 = W2[(k0 + 1) * 64 + lane];
      float w2 = W2[(k0 + 2) * 64 + lane];
      float w3 = W2[(k0 + 3) * 64 + lane];
#pragma unroll
      for (int s = 0; s < SPB4; ++s) {
        float4 x = *(float4*)&sA[s * 128 + k0];
        acc[s] += x.x * w0 + x.y * w1 + x.z * w2 + x.w * w3;
      }
    }
#pragma unroll
    for (int s = 0; s < SPB4; ++s) sP[wv * 256 + s * 64 + lane] = acc[s];
  }
  __syncthreads();
  {
    int o = t;
    float v = b2[o & 63] + sP[o] + sP[256 + o] + sP[512 + o] + sP[768 + o];
    sB[o] = v;
  }
  __syncthreads();
  {
    const int c = 64 * wv + lane;
    float acc[SPB4];
    float cb = c1[c];
#pragma unroll
    for (int s = 0; s < SPB4; ++s) acc[s] = cb;
    const float* wp = V1 + (size_t)64 * 256 + c;
#pragma unroll 4
    for (int m = 0; m < 16; ++m) {
      int k0 = 4 * m;
      float w0 = wp[(k0 + 0) * 256];
      float w1 = wp[(k0 + 1) * 256];
      float w2 = wp[(k0 + 2) * 256];
      float w3 = wp[(k0 + 3) * 256];
#pragma unroll
      for (int s = 0; s < SPB4; ++s) {
        float4 x = *(float4*)&sB[s * 64 + k0];
        acc[s] += x.x * w0 + x.y * w1 + x.z * w2 + x.w * w3;
      }
    }
#pragma unroll
    for (int s = 0; s < SPB4; ++s) sA[s * 256 + c] = siluf(acc[s]);
  }
  __syncthreads();
  {
    const int c = 64 * wv + lane;
    float acc[SPB4];
    float cb = c2[c];
#pragma unroll
    for (int s = 0; s < SPB4; ++s) acc[s] = cb;
    const float* wp = V2 + c;
#pragma unroll 4
    for (int m = 0; m < 64; ++m) {
      int k0 = 4 * m;
      float w0 = wp[(size_t)(k0 + 0) * 256];
      float w1 = wp[(size_t)(k0 + 1) * 256];
      float w2 = wp[(size_t)(k0 + 2) * 256];
      float w3 = wp[(size_t)(k0 + 3) * 256];
#pragma unroll
      for (int s = 0; s < SPB4; ++s) {
        float4 x = *(float4*)&sA[s * 256 + k0];
        acc[s] += x.x * w0 + x.y * w1 + x.z * w2 + x.w * w3;
      }
    }
#pragma unroll
    for (int s = 0; s < SPB4; ++s) sB[s * 256 + c] = siluf(acc[s]);
  }
  __syncthreads();
  {
    float acc[SPB4] = {};
    const int kb = 64 * wv;
#pragma unroll 4
    for (int m = 0; m < 16; ++m) {
      int k0 = kb + 4 * m;
      float w0 = V3[(k0 + 0) * 64 + lane];
      float w1 = V3[(k0 + 1) * 64 + lane];
      float w2 = V3[(k0 + 2) * 64 + lane];
      float w3 = V3[(k0 + 3) * 64 + lane];
#pragma unroll
      for (int s = 0; s < SPB4; ++s) {
        float4 x = *(float4*)&sB[s * 256 + k0];
        acc[s] += x.x * w0 + x.y * w1 + x.z * w2 + x.w * w3;
      }
    }
#pragma unroll
    for (int s = 0; s < SPB4; ++s) sP[wv * 256 + s * 64 + lane] = acc[s];
  }
  __syncthreads();
  {
    int b = bbase + wv;
    float blv = c3[lane] + sP[wv * 64 + lane] + sP[256 + wv * 64 + lane]
              + sP[512 + wv * 64 + lane] + sP[768 + wv * 64 + lane];
    float eb = expf(blv);
    float Zb = waveSum(eb);
    float lp = selectAndPL(blv, eb, Zb, ub + (size_t)b * 64,
                           out + (size_t)b * 128 + 64, lane,
                           sValsRow, sSelERow, nullptr);
    if (lane == 0)
      out[(size_t)8192 * 128 + b] = sLpA[wv] + lp;
  }
}

extern "C" void kernel_launch(void* const* d_in, const int* in_sizes, int n_in,
                              void* d_out, int out_size, void* d_ws, size_t ws_size,
                              hipStream_t stream) {
  const float* ua   = (const float*)d_in[0];
  const float* ub   = (const float*)d_in[1];
  const float* alog = (const float*)d_in[2];
  const float* W1   = (const float*)d_in[3];
  const float* b1   = (const float*)d_in[4];
  const float* W2   = (const float*)d_in[5];
  const float* b2   = (const float*)d_in[6];
  const float* V1   = (const float*)d_in[7];
  const float* c1   = (const float*)d_in[8];
  const float* V2   = (const float*)d_in[9];
  const float* c2   = (const float*)d_in[10];
  const float* V3   = (const float*)d_in[11];
  const float* c3   = (const float*)d_in[12];
  float* out = (float*)d_out;

  if (ws_size >= (size_t)WS_USHORTS * 2) {
    unsigned short* wt = (unsigned short*)d_ws;
    pcf_prep<<<dim3(52), dim3(256), 0, stream>>>(W2, V1, V2, V3, wt);
    pcf_mfma<<<dim3(8192 / SPB), dim3(NTH), 0, stream>>>(
        ua, ub, alog, W1, b1, b2, c1, c2, c3, wt, out);
  } else {
    pcf_small<<<dim3(8192 / SPB4), dim3(256), 0, stream>>>(
        ua, ub, alog, W1, b1, W2, b2, V1, c1, V2, c2, V3, c3, out);
  }
}